// Round 1
// baseline (2501.187 us; speedup 1.0000x reference)
//
#include <hip/hip_runtime.h>

#define N_NODES 100000
#define N_EDGES 1600000
#define N_GRAPHS 256
#define F_IN 32
#define F_HID 64
#define F_OUT 64

// ---------------- layer-1 edge scatter: agg1[dst] += x[src], F=32 ----------------
__global__ void scatter_l1(const float* __restrict__ x,
                           const int* __restrict__ src,
                           const int* __restrict__ dst,
                           float* __restrict__ agg) {
    int idx = blockIdx.x * blockDim.x + threadIdx.x;
    const int total = N_EDGES * (F_IN / 4);   // 8 float4 chunks per edge
    if (idx >= total) return;
    int e = idx >> 3;
    int c = idx & 7;
    int s = src[e];
    int d = dst[e];
    float4 v = *reinterpret_cast<const float4*>(x + (size_t)s * F_IN + c * 4);
    float* a = agg + (size_t)d * F_IN + c * 4;
    atomicAdd(a + 0, v.x);
    atomicAdd(a + 1, v.y);
    atomicAdd(a + 2, v.z);
    atomicAdd(a + 3, v.w);
}

// ---------------- layer-2 edge scatter: agg2[dst] += h1[src], F=64 ----------------
__global__ void scatter_l2(const float* __restrict__ h1,
                           const int* __restrict__ src,
                           const int* __restrict__ dst,
                           float* __restrict__ agg) {
    int idx = blockIdx.x * blockDim.x + threadIdx.x;
    const int total = N_EDGES * (F_HID / 4);  // 16 float4 chunks per edge
    if (idx >= total) return;
    int e = idx >> 4;
    int c = idx & 15;
    int s = src[e];
    int d = dst[e];
    float4 v = *reinterpret_cast<const float4*>(h1 + (size_t)s * F_HID + c * 4);
    float* a = agg + (size_t)d * F_HID + c * 4;
    atomicAdd(a + 0, v.x);
    atomicAdd(a + 1, v.y);
    atomicAdd(a + 2, v.z);
    atomicAdd(a + 3, v.w);
}

// ------------- node transform: hout = tanh(agg @ Wrel + b + hin @ Wroot) -------------
// FIN = input feature width (32 or 64), output width fixed at 64.
template <int FIN>
__global__ void node_transform(const float* __restrict__ agg,
                               const float* __restrict__ hin,
                               const float* __restrict__ Wrel,
                               const float* __restrict__ brel,
                               const float* __restrict__ Wroot,
                               float* __restrict__ hout) {
    __shared__ float sWrel[FIN * 64];
    __shared__ float sWroot[FIN * 64];
    __shared__ float sb[64];
    for (int i = threadIdx.x; i < FIN * 64; i += blockDim.x) {
        sWrel[i] = Wrel[i];
        sWroot[i] = Wroot[i];
    }
    if (threadIdx.x < 64) sb[threadIdx.x] = brel[threadIdx.x];
    __syncthreads();

    int gid = blockIdx.x * blockDim.x + threadIdx.x;
    int node = gid >> 6;   // 64 output feats per node
    int f = gid & 63;
    if (node >= N_NODES) return;

    const float* arow = agg + (size_t)node * FIN;
    const float* xrow = hin + (size_t)node * FIN;
    float acc = sb[f];
#pragma unroll
    for (int k = 0; k < FIN; ++k) {
        acc += arow[k] * sWrel[k * 64 + f] + xrow[k] * sWroot[k * 64 + f];
    }
    hout[(size_t)node * 64 + f] = tanhf(acc);
}

// ------------- layer-2 transform fused with mean-pool accumulation -------------
__global__ void node_transform2_pool(const float* __restrict__ agg,
                                     const float* __restrict__ h1,
                                     const float* __restrict__ Wrel,
                                     const float* __restrict__ brel,
                                     const float* __restrict__ Wroot,
                                     const int* __restrict__ batch,
                                     float* __restrict__ sums) {
    __shared__ float sWrel[F_HID * 64];
    __shared__ float sWroot[F_HID * 64];
    __shared__ float sb[64];
    for (int i = threadIdx.x; i < F_HID * 64; i += blockDim.x) {
        sWrel[i] = Wrel[i];
        sWroot[i] = Wroot[i];
    }
    if (threadIdx.x < 64) sb[threadIdx.x] = brel[threadIdx.x];
    __syncthreads();

    int gid = blockIdx.x * blockDim.x + threadIdx.x;
    int node = gid >> 6;
    int f = gid & 63;
    if (node >= N_NODES) return;

    const float* arow = agg + (size_t)node * F_HID;
    const float* xrow = h1 + (size_t)node * F_HID;
    float acc = sb[f];
#pragma unroll
    for (int k = 0; k < F_HID; ++k) {
        acc += arow[k] * sWrel[k * 64 + f] + xrow[k] * sWroot[k * 64 + f];
    }
    float h2 = tanhf(acc);
    int g = batch[node];
    atomicAdd(&sums[(size_t)g * 64 + f], h2);
}

__global__ void count_nodes(const int* __restrict__ batch, float* __restrict__ counts) {
    int i = blockIdx.x * blockDim.x + threadIdx.x;
    if (i < N_NODES) atomicAdd(&counts[batch[i]], 1.0f);
}

__global__ void finalize(const float* __restrict__ sums,
                         const float* __restrict__ counts,
                         float* __restrict__ out) {
    int i = blockIdx.x * blockDim.x + threadIdx.x;
    if (i < N_GRAPHS * 64) {
        float c = counts[i >> 6];
        out[i] = sums[i] / fmaxf(c, 1.0f);
    }
}

extern "C" void kernel_launch(void* const* d_in, const int* in_sizes, int n_in,
                              void* d_out, int out_size, void* d_ws, size_t ws_size,
                              hipStream_t stream) {
    const float* x       = (const float*)d_in[0];
    const int*   ei      = (const int*)d_in[1];   // (2, N_EDGES): row0=src, row1=dst
    const int*   batch   = (const int*)d_in[2];
    const float* W1_rel  = (const float*)d_in[3];
    const float* b1_rel  = (const float*)d_in[4];
    const float* W1_root = (const float*)d_in[5];
    const float* W2_rel  = (const float*)d_in[6];
    const float* b2_rel  = (const float*)d_in[7];
    const float* W2_root = (const float*)d_in[8];
    float* out = (float*)d_out;

    const int* src = ei;
    const int* dst = ei + N_EDGES;

    // Workspace layout: regions needing zero-init first (one contiguous memset).
    char* ws = (char*)d_ws;
    float* agg1   = (float*)ws;                       // N_NODES*32
    float* agg2   = (float*)(ws + (size_t)N_NODES * F_IN * 4);                       // N_NODES*64
    float* sums   = (float*)(ws + (size_t)N_NODES * (F_IN + F_HID) * 4);             // 256*64
    float* counts = (float*)(ws + (size_t)N_NODES * (F_IN + F_HID) * 4 + N_GRAPHS * F_OUT * 4);
    size_t zero_bytes = (size_t)N_NODES * (F_IN + F_HID) * 4 + (size_t)N_GRAPHS * F_OUT * 4 + N_GRAPHS * 4;
    float* h1     = (float*)(ws + zero_bytes);        // N_NODES*64, fully overwritten

    hipMemsetAsync(d_ws, 0, zero_bytes, stream);

    // Layer 1: scatter + transform
    {
        int total = N_EDGES * (F_IN / 4);
        scatter_l1<<<(total + 255) / 256, 256, 0, stream>>>(x, src, dst, agg1);
    }
    {
        int total = N_NODES * 64;
        node_transform<F_IN><<<(total + 255) / 256, 256, 0, stream>>>(
            agg1, x, W1_rel, b1_rel, W1_root, h1);
    }

    // Layer 2: scatter + transform fused with pooling
    {
        int total = N_EDGES * (F_HID / 4);
        scatter_l2<<<(total + 255) / 256, 256, 0, stream>>>(h1, src, dst, agg2);
    }
    {
        int total = N_NODES * 64;
        node_transform2_pool<<<(total + 255) / 256, 256, 0, stream>>>(
            agg2, h1, W2_rel, b2_rel, W2_root, batch, sums);
    }

    count_nodes<<<(N_NODES + 255) / 256, 256, 0, stream>>>(batch, counts);
    finalize<<<(N_GRAPHS * 64 + 255) / 256, 256, 0, stream>>>(sums, counts, out);
}

// Round 2
// 916.383 us; speedup vs baseline: 2.7294x; 2.7294x over previous
//
#include <hip/hip_runtime.h>

#define N_NODES 100000
#define N_EDGES 1600000
#define N_GRAPHS 256
#define F_IN 32
#define F_HID 64
#define F_OUT 64

// ---------------- CSR build ----------------
__global__ void histogram_dst(const int* __restrict__ dst, int* __restrict__ deg) {
    int e = blockIdx.x * blockDim.x + threadIdx.x;
    if (e < N_EDGES) atomicAdd(&deg[dst[e]], 1);
}

// Block-local inclusive scan (256 elems/block); writes local-inclusive to end[], block total to partials[]
__global__ void scan1(const int* __restrict__ deg, int* __restrict__ end_, int* __restrict__ partials) {
    __shared__ int s[256];
    int tid = threadIdx.x;
    int i = blockIdx.x * 256 + tid;
    int v = (i < N_NODES) ? deg[i] : 0;
    s[tid] = v;
    __syncthreads();
#pragma unroll
    for (int off = 1; off < 256; off <<= 1) {
        int t = 0;
        if (tid >= off) t = s[tid - off];
        __syncthreads();
        if (tid >= off) s[tid] += t;
        __syncthreads();
    }
    if (i < N_NODES) end_[i] = s[tid];
    if (tid == 255) partials[blockIdx.x] = s[255];
}

// Exclusive scan of block partials (NB <= 512), single block
__global__ void scan2(int* __restrict__ partials, int nb) {
    __shared__ int s[512];
    int tid = threadIdx.x;
    int v = (tid < nb) ? partials[tid] : 0;
    s[tid] = v;
    __syncthreads();
#pragma unroll
    for (int off = 1; off < 512; off <<= 1) {
        int t = 0;
        if (tid >= off) t = s[tid - off];
        __syncthreads();
        if (tid >= off) s[tid] += t;
        __syncthreads();
    }
    int excl = (tid > 0) ? s[tid - 1] : 0;
    if (tid < nb) partials[tid] = excl;
}

// end_ becomes global inclusive prefix; cursor = start offset
__global__ void scan3(const int* __restrict__ deg, int* __restrict__ end_,
                      int* __restrict__ cursor, const int* __restrict__ partials) {
    int i = blockIdx.x * 256 + threadIdx.x;
    if (i < N_NODES) {
        int e = end_[i] + partials[blockIdx.x];
        end_[i] = e;
        cursor[i] = e - deg[i];
    }
}

__global__ void fill_adj(const int* __restrict__ src, const int* __restrict__ dst,
                         int* __restrict__ cursor, int* __restrict__ adj) {
    int e = blockIdx.x * blockDim.x + threadIdx.x;
    if (e < N_EDGES) {
        int d = dst[e];
        int pos = atomicAdd(&cursor[d], 1);
        adj[pos] = src[e];
    }
}

// ---------------- fused layer: gather + linear + tanh (+ optional pool) ----------------
// One wave per node. Lane f accumulates agg[f] over neighbors, then the
// 64-wide transform is done via wave shuffles broadcasting agg[k]/x[k].
template <int FIN, bool POOL>
__global__ __launch_bounds__(256) void layer_fused(
    const float* __restrict__ hin,
    const int* __restrict__ adj, const int* __restrict__ end_, const int* __restrict__ deg,
    const float* __restrict__ Wrel, const float* __restrict__ brel, const float* __restrict__ Wroot,
    float* __restrict__ hout,              // used when !POOL
    const int* __restrict__ batch,         // used when POOL
    float* __restrict__ sums) {            // used when POOL
    __shared__ float sWrel[FIN * 64];
    __shared__ float sWroot[FIN * 64];
    __shared__ float sb[64];
    for (int i = threadIdx.x; i < FIN * 64; i += 256) {
        sWrel[i] = Wrel[i];
        sWroot[i] = Wroot[i];
    }
    if (threadIdx.x < 64) sb[threadIdx.x] = brel[threadIdx.x];
    __syncthreads();

    int wave = threadIdx.x >> 6;
    int lane = threadIdx.x & 63;
    int node = blockIdx.x * 4 + wave;
    if (node >= N_NODES) return;

    int eend = end_[node];
    int d = deg[node];
    int s = eend - d;

    float acc = 0.0f;
    float xv;
    if (FIN == 64) {
        for (int i = s; i < eend; ++i) {
            int sn = adj[i];
            acc += hin[(size_t)sn * 64 + lane];
        }
        xv = hin[(size_t)node * 64 + lane];
    } else {
        // 32 features: two neighbors in flight (lane = hi*32 + f)
        int f = lane & 31;
        int hi = lane >> 5;
        for (int i = s + hi; i < eend; i += 2) {
            int sn = adj[i];
            acc += hin[(size_t)sn * 32 + f];
        }
        acc += __shfl_xor(acc, 32);   // both halves now hold full agg[f]
        xv = hin[(size_t)node * 32 + f];
    }

    float o = sb[lane];
#pragma unroll
    for (int k = 0; k < FIN; ++k) {
        float ak = __shfl(acc, k);
        float xk = __shfl(xv, k);
        o += ak * sWrel[k * 64 + lane] + xk * sWroot[k * 64 + lane];
    }
    o = tanhf(o);

    if (POOL) {
        int g = batch[node];
        atomicAdd(&sums[(size_t)g * 64 + lane], o);
    } else {
        hout[(size_t)node * 64 + lane] = o;
    }
}

__global__ void count_nodes(const int* __restrict__ batch, float* __restrict__ counts) {
    int i = blockIdx.x * blockDim.x + threadIdx.x;
    if (i < N_NODES) atomicAdd(&counts[batch[i]], 1.0f);
}

__global__ void finalize(const float* __restrict__ sums,
                         const float* __restrict__ counts,
                         float* __restrict__ out) {
    int i = blockIdx.x * blockDim.x + threadIdx.x;
    if (i < N_GRAPHS * 64) {
        float c = counts[i >> 6];
        out[i] = sums[i] / fmaxf(c, 1.0f);
    }
}

extern "C" void kernel_launch(void* const* d_in, const int* in_sizes, int n_in,
                              void* d_out, int out_size, void* d_ws, size_t ws_size,
                              hipStream_t stream) {
    const float* x       = (const float*)d_in[0];
    const int*   ei      = (const int*)d_in[1];
    const int*   batch   = (const int*)d_in[2];
    const float* W1_rel  = (const float*)d_in[3];
    const float* b1_rel  = (const float*)d_in[4];
    const float* W1_root = (const float*)d_in[5];
    const float* W2_rel  = (const float*)d_in[6];
    const float* b2_rel  = (const float*)d_in[7];
    const float* W2_root = (const float*)d_in[8];
    float* out = (float*)d_out;

    const int* src = ei;
    const int* dst = ei + N_EDGES;

    // ---- workspace layout (bytes) ----
    char* ws = (char*)d_ws;
    int*   deg      = (int*)(ws + 0);                 // 400000 B
    float* sums     = (float*)(ws + 400000);          // 65536 B
    float* counts   = (float*)(ws + 465536);          // 1024 B
    // ---- zero boundary: 466560 ----
    int*   end_     = (int*)(ws + 466560);            // 400000 B
    int*   cursor   = (int*)(ws + 866560);            // 400000 B
    int*   partials = (int*)(ws + 1266560);           // 2048 B
    int*   adj      = (int*)(ws + 1268608);           // 6400000 B
    float* h1       = (float*)(ws + 7668736);         // 25600000 B  (aligned 256)

    hipMemsetAsync(d_ws, 0, 466560, stream);

    // ---- CSR build ----
    const int NB_NODE = (N_NODES + 255) / 256;        // 391
    histogram_dst<<<(N_EDGES + 255) / 256, 256, 0, stream>>>(dst, deg);
    scan1<<<NB_NODE, 256, 0, stream>>>(deg, end_, partials);
    scan2<<<1, 512, 0, stream>>>(partials, NB_NODE);
    scan3<<<NB_NODE, 256, 0, stream>>>(deg, end_, cursor, partials);
    fill_adj<<<(N_EDGES + 255) / 256, 256, 0, stream>>>(src, dst, cursor, adj);

    // ---- fused layers ----
    const int NB_LAYER = (N_NODES + 3) / 4;           // 25000 blocks, 4 waves each
    layer_fused<F_IN, false><<<NB_LAYER, 256, 0, stream>>>(
        x, adj, end_, deg, W1_rel, b1_rel, W1_root, h1, nullptr, nullptr);
    layer_fused<F_HID, true><<<NB_LAYER, 256, 0, stream>>>(
        h1, adj, end_, deg, W2_rel, b2_rel, W2_root, nullptr, batch, sums);

    count_nodes<<<(N_NODES + 255) / 256, 256, 0, stream>>>(batch, counts);
    finalize<<<(N_GRAPHS * 64 + 255) / 256, 256, 0, stream>>>(sums, counts, out);
}

// Round 3
// 681.831 us; speedup vs baseline: 3.6683x; 1.3440x over previous
//
#include <hip/hip_runtime.h>

#define N_NODES 100000
#define N_EDGES 1600000
#define N_GRAPHS 256
#define F_IN 32
#define F_HID 64
#define F_OUT 64

// ---------------- CSR build ----------------
__global__ void histogram_dst(const int* __restrict__ dst, int* __restrict__ deg) {
    int e = blockIdx.x * blockDim.x + threadIdx.x;
    if (e < N_EDGES) atomicAdd(&deg[dst[e]], 1);
}

__global__ void scan1(const int* __restrict__ deg, int* __restrict__ end_, int* __restrict__ partials) {
    __shared__ int s[256];
    int tid = threadIdx.x;
    int i = blockIdx.x * 256 + tid;
    int v = (i < N_NODES) ? deg[i] : 0;
    s[tid] = v;
    __syncthreads();
#pragma unroll
    for (int off = 1; off < 256; off <<= 1) {
        int t = 0;
        if (tid >= off) t = s[tid - off];
        __syncthreads();
        if (tid >= off) s[tid] += t;
        __syncthreads();
    }
    if (i < N_NODES) end_[i] = s[tid];
    if (tid == 255) partials[blockIdx.x] = s[255];
}

__global__ void scan2(int* __restrict__ partials, int nb) {
    __shared__ int s[512];
    int tid = threadIdx.x;
    int v = (tid < nb) ? partials[tid] : 0;
    s[tid] = v;
    __syncthreads();
#pragma unroll
    for (int off = 1; off < 512; off <<= 1) {
        int t = 0;
        if (tid >= off) t = s[tid - off];
        __syncthreads();
        if (tid >= off) s[tid] += t;
        __syncthreads();
    }
    int excl = (tid > 0) ? s[tid - 1] : 0;
    if (tid < nb) partials[tid] = excl;
}

__global__ void scan3(const int* __restrict__ deg, int* __restrict__ end_,
                      int* __restrict__ cursor, const int* __restrict__ partials) {
    int i = blockIdx.x * 256 + threadIdx.x;
    if (i < N_NODES) {
        int e = end_[i] + partials[blockIdx.x];
        end_[i] = e;
        cursor[i] = e - deg[i];
    }
}

__global__ void fill_adj(const int* __restrict__ src, const int* __restrict__ dst,
                         int* __restrict__ cursor, int* __restrict__ adj) {
    int e = blockIdx.x * blockDim.x + threadIdx.x;
    if (e < N_EDGES) {
        int d = dst[e];
        int pos = atomicAdd(&cursor[d], 1);
        adj[pos] = src[e];
    }
}

// ---------------- pure gathers (no LDS, max occupancy, ILP-4) ----------------
// One wave per node, lane = feature. Neighbor IDs preloaded 64 at a time.
__global__ __launch_bounds__(256) void gather64(const float* __restrict__ h,
        const int* __restrict__ adj, const int* __restrict__ end_, const int* __restrict__ deg,
        float* __restrict__ agg) {
    int wid = (blockIdx.x * blockDim.x + threadIdx.x) >> 6;
    int lane = threadIdx.x & 63;
    if (wid >= N_NODES) return;
    int e = end_[wid];
    int d = deg[wid];
    int s = e - d;
    float acc = 0.0f;
    for (int base = 0; base < d; base += 64) {
        int chunk = min(64, d - base);
        int myadj = (base + lane < d) ? adj[s + base + lane] : 0;
        int j = 0;
        for (; j + 4 <= chunk; j += 4) {
            int s0 = __shfl(myadj, j);
            int s1 = __shfl(myadj, j + 1);
            int s2 = __shfl(myadj, j + 2);
            int s3 = __shfl(myadj, j + 3);
            float v0 = h[(size_t)s0 * 64 + lane];
            float v1 = h[(size_t)s1 * 64 + lane];
            float v2 = h[(size_t)s2 * 64 + lane];
            float v3 = h[(size_t)s3 * 64 + lane];
            acc += v0 + v1 + v2 + v3;
        }
        for (; j < chunk; ++j) {
            int sn = __shfl(myadj, j);
            acc += h[(size_t)sn * 64 + lane];
        }
    }
    agg[(size_t)wid * 64 + lane] = acc;
}

// Half-wave per node (F=32): lane = hw*32 + f.
__global__ __launch_bounds__(256) void gather32(const float* __restrict__ xin,
        const int* __restrict__ adj, const int* __restrict__ end_, const int* __restrict__ deg,
        float* __restrict__ agg) {
    int wid = (blockIdx.x * blockDim.x + threadIdx.x) >> 6;
    int lane = threadIdx.x & 63;
    int hw = lane >> 5;
    int f = lane & 31;
    int node = wid * 2 + hw;
    if (node >= N_NODES) return;
    int e = end_[node];
    int d = deg[node];
    int s = e - d;
    float acc = 0.0f;
    for (int base = 0; base < d; base += 32) {
        int chunk = min(32, d - base);
        int myadj = (base + f < d) ? adj[s + base + f] : 0;
        int j = 0;
        for (; j + 4 <= chunk; j += 4) {
            int s0 = __shfl(myadj, hw * 32 + j);
            int s1 = __shfl(myadj, hw * 32 + j + 1);
            int s2 = __shfl(myadj, hw * 32 + j + 2);
            int s3 = __shfl(myadj, hw * 32 + j + 3);
            float v0 = xin[(size_t)s0 * 32 + f];
            float v1 = xin[(size_t)s1 * 32 + f];
            float v2 = xin[(size_t)s2 * 32 + f];
            float v3 = xin[(size_t)s3 * 32 + f];
            acc += v0 + v1 + v2 + v3;
        }
        for (; j < chunk; ++j) {
            int sn = __shfl(myadj, hw * 32 + j);
            acc += xin[(size_t)sn * 32 + f];
        }
    }
    agg[(size_t)node * 32 + f] = acc;
}

// ---------------- dense transforms ----------------
__global__ __launch_bounds__(256) void transform1(const float* __restrict__ agg,
        const float* __restrict__ xin,
        const float* __restrict__ Wrel, const float* __restrict__ brel,
        const float* __restrict__ Wroot,
        float* __restrict__ h1) {
    __shared__ float sW[2 * 32 * 64 + 64];
    for (int i = threadIdx.x; i < 32 * 64; i += 256) {
        sW[i] = Wrel[i];
        sW[2048 + i] = Wroot[i];
    }
    if (threadIdx.x < 64) sW[4096 + threadIdx.x] = brel[threadIdx.x];
    __syncthreads();
    int gid = blockIdx.x * 256 + threadIdx.x;
    int node = gid >> 6;
    int fo = gid & 63;
    if (node >= N_NODES) return;
    const float* ar = agg + (size_t)node * 32;
    const float* xr = xin + (size_t)node * 32;
    float o = sW[4096 + fo];
#pragma unroll
    for (int k = 0; k < 32; ++k) {
        o += ar[k] * sW[k * 64 + fo] + xr[k] * sW[2048 + k * 64 + fo];
    }
    h1[(size_t)node * 64 + fo] = tanhf(o);
}

__global__ __launch_bounds__(256) void transform2_pool(const float* __restrict__ agg,
        const float* __restrict__ h1,
        const float* __restrict__ Wrel, const float* __restrict__ brel,
        const float* __restrict__ Wroot,
        const int* __restrict__ batch,
        float* __restrict__ sums) {
    __shared__ float sW[2 * 64 * 64 + 64];
    for (int i = threadIdx.x; i < 64 * 64; i += 256) {
        sW[i] = Wrel[i];
        sW[4096 + i] = Wroot[i];
    }
    if (threadIdx.x < 64) sW[8192 + threadIdx.x] = brel[threadIdx.x];
    __syncthreads();
    int gid = blockIdx.x * 256 + threadIdx.x;
    int node = gid >> 6;
    int fo = gid & 63;
    if (node >= N_NODES) return;
    const float* ar = agg + (size_t)node * 64;
    const float* xr = h1 + (size_t)node * 64;
    float o = sW[8192 + fo];
#pragma unroll
    for (int k = 0; k < 64; ++k) {
        o += ar[k] * sW[k * 64 + fo] + xr[k] * sW[4096 + k * 64 + fo];
    }
    float h2 = tanhf(o);
    int g = batch[node];
    atomicAdd(&sums[(size_t)g * 64 + fo], h2);
}

__global__ void count_nodes(const int* __restrict__ batch, float* __restrict__ counts) {
    int i = blockIdx.x * blockDim.x + threadIdx.x;
    if (i < N_NODES) atomicAdd(&counts[batch[i]], 1.0f);
}

__global__ void finalize(const float* __restrict__ sums,
                         const float* __restrict__ counts,
                         float* __restrict__ out) {
    int i = blockIdx.x * blockDim.x + threadIdx.x;
    if (i < N_GRAPHS * 64) {
        float c = counts[i >> 6];
        out[i] = sums[i] / fmaxf(c, 1.0f);
    }
}

extern "C" void kernel_launch(void* const* d_in, const int* in_sizes, int n_in,
                              void* d_out, int out_size, void* d_ws, size_t ws_size,
                              hipStream_t stream) {
    const float* x       = (const float*)d_in[0];
    const int*   ei      = (const int*)d_in[1];
    const int*   batch   = (const int*)d_in[2];
    const float* W1_rel  = (const float*)d_in[3];
    const float* b1_rel  = (const float*)d_in[4];
    const float* W1_root = (const float*)d_in[5];
    const float* W2_rel  = (const float*)d_in[6];
    const float* b2_rel  = (const float*)d_in[7];
    const float* W2_root = (const float*)d_in[8];
    float* out = (float*)d_out;

    const int* src = ei;
    const int* dst = ei + N_EDGES;

    // ---- workspace layout (bytes) ----
    char* ws = (char*)d_ws;
    int*   deg      = (int*)(ws + 0);                 // 400000
    float* sums     = (float*)(ws + 400000);          // 65536
    float* counts   = (float*)(ws + 465536);          // 1024
    // ---- zero boundary: 466560 ----
    int*   end_     = (int*)(ws + 466560);            // 400000
    int*   cursor   = (int*)(ws + 866560);            // 400000
    int*   partials = (int*)(ws + 1266560);           // 2048
    int*   adj      = (int*)(ws + 1268608);           // 6400000
    float* aggbuf   = (float*)(ws + 7668608);         // 25600000 (shared by agg1/agg2)
    float* h1       = (float*)(ws + 33268608);        // 25600000

    hipMemsetAsync(d_ws, 0, 466560, stream);

    // ---- CSR build ----
    const int NB_NODE = (N_NODES + 255) / 256;
    histogram_dst<<<(N_EDGES + 255) / 256, 256, 0, stream>>>(dst, deg);
    scan1<<<NB_NODE, 256, 0, stream>>>(deg, end_, partials);
    scan2<<<1, 512, 0, stream>>>(partials, NB_NODE);
    scan3<<<NB_NODE, 256, 0, stream>>>(deg, end_, cursor, partials);
    fill_adj<<<(N_EDGES + 255) / 256, 256, 0, stream>>>(src, dst, cursor, adj);

    // ---- layer 1 ----
    gather32<<<((N_NODES + 1) / 2 * 64 + 255) / 256, 256, 0, stream>>>(x, adj, end_, deg, aggbuf);
    transform1<<<(N_NODES * 64 + 255) / 256, 256, 0, stream>>>(aggbuf, x, W1_rel, b1_rel, W1_root, h1);

    // ---- layer 2 ----
    gather64<<<(N_NODES * 64 + 255) / 256, 256, 0, stream>>>(h1, adj, end_, deg, aggbuf);
    transform2_pool<<<(N_NODES * 64 + 255) / 256, 256, 0, stream>>>(aggbuf, h1, W2_rel, b2_rel, W2_root, batch, sums);

    count_nodes<<<(N_NODES + 255) / 256, 256, 0, stream>>>(batch, counts);
    finalize<<<(N_GRAPHS * 64 + 255) / 256, 256, 0, stream>>>(sums, counts, out);
}

// Round 6
// 499.580 us; speedup vs baseline: 5.0066x; 1.3648x over previous
//
#include <hip/hip_runtime.h>

#define N_NODES 100000
#define N_EDGES 1600000
#define N_GRAPHS 256
#define F_IN 32
#define F_HID 64
#define F_OUT 64

// ---------------- CSR build ----------------
__global__ void histogram_dst(const int* __restrict__ dst, int* __restrict__ deg) {
    int e = blockIdx.x * blockDim.x + threadIdx.x;
    if (e < N_EDGES) atomicAdd(&deg[dst[e]], 1);
}

__global__ void scan1(const int* __restrict__ deg, int* __restrict__ end_, int* __restrict__ partials) {
    __shared__ int s[256];
    int tid = threadIdx.x;
    int i = blockIdx.x * 256 + tid;
    int v = (i < N_NODES) ? deg[i] : 0;
    s[tid] = v;
    __syncthreads();
#pragma unroll
    for (int off = 1; off < 256; off <<= 1) {
        int t = 0;
        if (tid >= off) t = s[tid - off];
        __syncthreads();
        if (tid >= off) s[tid] += t;
        __syncthreads();
    }
    if (i < N_NODES) end_[i] = s[tid];
    if (tid == 255) partials[blockIdx.x] = s[255];
}

__global__ void scan2(int* __restrict__ partials, int nb) {
    __shared__ int s[512];
    int tid = threadIdx.x;
    int v = (tid < nb) ? partials[tid] : 0;
    s[tid] = v;
    __syncthreads();
#pragma unroll
    for (int off = 1; off < 512; off <<= 1) {
        int t = 0;
        if (tid >= off) t = s[tid - off];
        __syncthreads();
        if (tid >= off) s[tid] += t;
        __syncthreads();
    }
    int excl = (tid > 0) ? s[tid - 1] : 0;
    if (tid < nb) partials[tid] = excl;
}

__global__ void scan3(const int* __restrict__ deg, int* __restrict__ end_,
                      int* __restrict__ cursor, const int* __restrict__ partials) {
    int i = blockIdx.x * 256 + threadIdx.x;
    if (i < N_NODES) {
        int e = end_[i] + partials[blockIdx.x];
        end_[i] = e;
        cursor[i] = e - deg[i];
    }
}

__global__ void fill_adj(const int* __restrict__ src, const int* __restrict__ dst,
                         int* __restrict__ cursor, int* __restrict__ adj) {
    int e = blockIdx.x * blockDim.x + threadIdx.x;
    if (e < N_EDGES) {
        int d = dst[e];
        int pos = atomicAdd(&cursor[d], 1);
        adj[pos] = src[e];
    }
}

// ---------------- pure gathers ----------------
__global__ __launch_bounds__(256) void gather64(const float* __restrict__ h,
        const int* __restrict__ adj, const int* __restrict__ end_, const int* __restrict__ deg,
        float* __restrict__ agg) {
    int wid = (blockIdx.x * blockDim.x + threadIdx.x) >> 6;
    int lane = threadIdx.x & 63;
    if (wid >= N_NODES) return;
    int e = end_[wid];
    int d = deg[wid];
    int s = e - d;
    float acc = 0.0f;
    for (int base = 0; base < d; base += 64) {
        int chunk = min(64, d - base);
        int myadj = (base + lane < d) ? adj[s + base + lane] : 0;
        int j = 0;
        for (; j + 4 <= chunk; j += 4) {
            int s0 = __shfl(myadj, j);
            int s1 = __shfl(myadj, j + 1);
            int s2 = __shfl(myadj, j + 2);
            int s3 = __shfl(myadj, j + 3);
            float v0 = h[(size_t)s0 * 64 + lane];
            float v1 = h[(size_t)s1 * 64 + lane];
            float v2 = h[(size_t)s2 * 64 + lane];
            float v3 = h[(size_t)s3 * 64 + lane];
            acc += v0 + v1 + v2 + v3;
        }
        for (; j < chunk; ++j) {
            int sn = __shfl(myadj, j);
            acc += h[(size_t)sn * 64 + lane];
        }
    }
    agg[(size_t)wid * 64 + lane] = acc;
}

__global__ __launch_bounds__(256) void gather32(const float* __restrict__ xin,
        const int* __restrict__ adj, const int* __restrict__ end_, const int* __restrict__ deg,
        float* __restrict__ agg) {
    int wid = (blockIdx.x * blockDim.x + threadIdx.x) >> 6;
    int lane = threadIdx.x & 63;
    int hw = lane >> 5;
    int f = lane & 31;
    int node = wid * 2 + hw;
    if (node >= N_NODES) return;
    int e = end_[node];
    int d = deg[node];
    int s = e - d;
    float acc = 0.0f;
    for (int base = 0; base < d; base += 32) {
        int chunk = min(32, d - base);
        int myadj = (base + f < d) ? adj[s + base + f] : 0;
        int j = 0;
        for (; j + 4 <= chunk; j += 4) {
            int s0 = __shfl(myadj, hw * 32 + j);
            int s1 = __shfl(myadj, hw * 32 + j + 1);
            int s2 = __shfl(myadj, hw * 32 + j + 2);
            int s3 = __shfl(myadj, hw * 32 + j + 3);
            float v0 = xin[(size_t)s0 * 32 + f];
            float v1 = xin[(size_t)s1 * 32 + f];
            float v2 = xin[(size_t)s2 * 32 + f];
            float v3 = xin[(size_t)s3 * 32 + f];
            acc += v0 + v1 + v2 + v3;
        }
        for (; j < chunk; ++j) {
            int sn = __shfl(myadj, hw * 32 + j);
            acc += xin[(size_t)sn * 32 + f];
        }
    }
    agg[(size_t)node * 32 + f] = acc;
}

// ---------------- dense transforms ----------------
__global__ __launch_bounds__(256) void transform1(const float* __restrict__ agg,
        const float* __restrict__ xin,
        const float* __restrict__ Wrel, const float* __restrict__ brel,
        const float* __restrict__ Wroot,
        float* __restrict__ h1) {
    __shared__ float sW[2 * 32 * 64 + 64];
    for (int i = threadIdx.x; i < 32 * 64; i += 256) {
        sW[i] = Wrel[i];
        sW[2048 + i] = Wroot[i];
    }
    if (threadIdx.x < 64) sW[4096 + threadIdx.x] = brel[threadIdx.x];
    __syncthreads();
    int gid = blockIdx.x * 256 + threadIdx.x;
    int node = gid >> 6;
    int fo = gid & 63;
    if (node >= N_NODES) return;
    const float* ar = agg + (size_t)node * 32;
    const float* xr = xin + (size_t)node * 32;
    float o = sW[4096 + fo];
#pragma unroll
    for (int k = 0; k < 32; ++k) {
        o += ar[k] * sW[k * 64 + fo] + xr[k] * sW[2048 + k * 64 + fo];
    }
    h1[(size_t)node * 64 + fo] = tanhf(o);
}

// layer-2 transform + pool with per-block reduction before the atomic.
// batch is sorted, so the (up to 4) nodes in a block usually share one graph.
__global__ __launch_bounds__(256) void transform2_pool(const float* __restrict__ agg,
        const float* __restrict__ h1,
        const float* __restrict__ Wrel, const float* __restrict__ brel,
        const float* __restrict__ Wroot,
        const int* __restrict__ batch,
        float* __restrict__ sums) {
    __shared__ float sW[2 * 64 * 64 + 64];
    __shared__ float red[256];
    __shared__ int sg[4];
    for (int i = threadIdx.x; i < 64 * 64; i += 256) {
        sW[i] = Wrel[i];
        sW[4096 + i] = Wroot[i];
    }
    if (threadIdx.x < 64) sW[8192 + threadIdx.x] = brel[threadIdx.x];
    __syncthreads();

    int gid = blockIdx.x * 256 + threadIdx.x;
    int node = gid >> 6;
    int fo = gid & 63;
    int wave = threadIdx.x >> 6;
    bool valid = node < N_NODES;

    float h2 = 0.0f;
    int g = -1;
    if (valid) {
        const float* ar = agg + (size_t)node * 64;
        const float* xr = h1 + (size_t)node * 64;
        float o = sW[8192 + fo];
#pragma unroll
        for (int k = 0; k < 64; ++k) {
            o += ar[k] * sW[k * 64 + fo] + xr[k] * sW[4096 + k * 64 + fo];
        }
        h2 = tanhf(o);
        g = batch[node];
    }
    red[threadIdx.x] = h2;
    if (fo == 0) sg[wave] = g;
    __syncthreads();

    if (valid) {
        int gprev = (wave > 0) ? sg[wave - 1] : -2;
        if (gprev != g) {          // this wave is the leader for graph g in this block
            float sum = h2;
            for (int w2 = wave + 1; w2 < 4; ++w2) {
                if (sg[w2] == g) sum += red[w2 * 64 + fo];
                else break;        // sorted: same-g waves are contiguous
            }
            atomicAdd(&sums[(size_t)g * 64 + fo], sum);
        }
    }
}

// counts[g] via binary search over the SORTED batch array (replaces atomic histogram)
__global__ void graph_counts(const int* __restrict__ batch, float* __restrict__ counts) {
    int g = threadIdx.x;
    if (g >= N_GRAPHS) return;
    int lo = 0, hi = N_NODES;
    while (lo < hi) { int mid = (lo + hi) >> 1; if (batch[mid] < g) lo = mid + 1; else hi = mid; }
    int start = lo;
    lo = 0; hi = N_NODES;
    while (lo < hi) { int mid = (lo + hi) >> 1; if (batch[mid] <= g) lo = mid + 1; else hi = mid; }
    counts[g] = (float)(lo - start);
}

__global__ void finalize(const float* __restrict__ sums,
                         const float* __restrict__ counts,
                         float* __restrict__ out) {
    int i = blockIdx.x * blockDim.x + threadIdx.x;
    if (i < N_GRAPHS * 64) {
        float c = counts[i >> 6];
        out[i] = sums[i] / fmaxf(c, 1.0f);
    }
}

extern "C" void kernel_launch(void* const* d_in, const int* in_sizes, int n_in,
                              void* d_out, int out_size, void* d_ws, size_t ws_size,
                              hipStream_t stream) {
    const float* x       = (const float*)d_in[0];
    const int*   ei      = (const int*)d_in[1];
    const int*   batch   = (const int*)d_in[2];
    const float* W1_rel  = (const float*)d_in[3];
    const float* b1_rel  = (const float*)d_in[4];
    const float* W1_root = (const float*)d_in[5];
    const float* W2_rel  = (const float*)d_in[6];
    const float* b2_rel  = (const float*)d_in[7];
    const float* W2_root = (const float*)d_in[8];
    float* out = (float*)d_out;

    const int* src = ei;
    const int* dst = ei + N_EDGES;

    // ---- workspace layout (bytes) ----
    char* ws = (char*)d_ws;
    int*   deg      = (int*)(ws + 0);                 // 400000
    float* sums     = (float*)(ws + 400000);          // 65536
    float* counts   = (float*)(ws + 465536);          // 1024
    // ---- zero boundary: 466560 ----
    int*   end_     = (int*)(ws + 466560);            // 400000
    int*   cursor   = (int*)(ws + 866560);            // 400000
    int*   partials = (int*)(ws + 1266560);           // 2048
    int*   adj      = (int*)(ws + 1268608);           // 6400000
    float* aggbuf   = (float*)(ws + 7668608);         // 25600000 (agg1/agg2 shared)
    float* h1       = (float*)(ws + 33268608);        // 25600000

    hipMemsetAsync(d_ws, 0, 466560, stream);

    // ---- CSR build ----
    const int NB_NODE = (N_NODES + 255) / 256;
    histogram_dst<<<(N_EDGES + 255) / 256, 256, 0, stream>>>(dst, deg);
    scan1<<<NB_NODE, 256, 0, stream>>>(deg, end_, partials);
    scan2<<<1, 512, 0, stream>>>(partials, NB_NODE);
    scan3<<<NB_NODE, 256, 0, stream>>>(deg, end_, cursor, partials);
    fill_adj<<<(N_EDGES + 255) / 256, 256, 0, stream>>>(src, dst, cursor, adj);

    // ---- layer 1 ----
    gather32<<<((N_NODES + 1) / 2 * 64 + 255) / 256, 256, 0, stream>>>(x, adj, end_, deg, aggbuf);
    transform1<<<(N_NODES * 64 + 255) / 256, 256, 0, stream>>>(aggbuf, x, W1_rel, b1_rel, W1_root, h1);

    // ---- layer 2 ----
    gather64<<<(N_NODES * 64 + 255) / 256, 256, 0, stream>>>(h1, adj, end_, deg, aggbuf);
    transform2_pool<<<(N_NODES * 64 + 255) / 256, 256, 0, stream>>>(aggbuf, h1, W2_rel, b2_rel, W2_root, batch, sums);

    graph_counts<<<1, 256, 0, stream>>>(batch, counts);
    finalize<<<(N_GRAPHS * 64 + 255) / 256, 256, 0, stream>>>(sums, counts, out);
}

// Round 7
// 431.375 us; speedup vs baseline: 5.7982x; 1.1581x over previous
//
#include <hip/hip_runtime.h>

#define N_NODES 100000
#define N_EDGES 1600000
#define N_GRAPHS 256
#define F_IN 32
#define F_HID 64
#define F_OUT 64

#define T_WAVES 2048            // waves for register-transform kernels (512 blocks x 4 waves)
#define NODES_PER_WAVE ((N_NODES + T_WAVES - 1) / T_WAVES)   // 49

// ---------------- CSR build ----------------
__global__ void histogram_dst(const int* __restrict__ dst, int* __restrict__ deg) {
    int e = blockIdx.x * blockDim.x + threadIdx.x;
    if (e < N_EDGES) atomicAdd(&deg[dst[e]], 1);
}

__global__ void scan1(const int* __restrict__ deg, int* __restrict__ end_, int* __restrict__ partials) {
    __shared__ int s[256];
    int tid = threadIdx.x;
    int i = blockIdx.x * 256 + tid;
    int v = (i < N_NODES) ? deg[i] : 0;
    s[tid] = v;
    __syncthreads();
#pragma unroll
    for (int off = 1; off < 256; off <<= 1) {
        int t = 0;
        if (tid >= off) t = s[tid - off];
        __syncthreads();
        if (tid >= off) s[tid] += t;
        __syncthreads();
    }
    if (i < N_NODES) end_[i] = s[tid];
    if (tid == 255) partials[blockIdx.x] = s[255];
}

__global__ void scan2(int* __restrict__ partials, int nb) {
    __shared__ int s[512];
    int tid = threadIdx.x;
    int v = (tid < nb) ? partials[tid] : 0;
    s[tid] = v;
    __syncthreads();
#pragma unroll
    for (int off = 1; off < 512; off <<= 1) {
        int t = 0;
        if (tid >= off) t = s[tid - off];
        __syncthreads();
        if (tid >= off) s[tid] += t;
        __syncthreads();
    }
    int excl = (tid > 0) ? s[tid - 1] : 0;
    if (tid < nb) partials[tid] = excl;
}

__global__ void scan3(const int* __restrict__ deg, int* __restrict__ end_,
                      int* __restrict__ cursor, const int* __restrict__ partials) {
    int i = blockIdx.x * 256 + threadIdx.x;
    if (i < N_NODES) {
        int e = end_[i] + partials[blockIdx.x];
        end_[i] = e;
        cursor[i] = e - deg[i];
    }
}

__global__ void fill_adj(const int* __restrict__ src, const int* __restrict__ dst,
                         int* __restrict__ cursor, int* __restrict__ adj) {
    int e = blockIdx.x * blockDim.x + threadIdx.x;
    if (e < N_EDGES) {
        int d = dst[e];
        int pos = atomicAdd(&cursor[d], 1);
        adj[pos] = src[e];
    }
}

// ---------------- pure gathers ----------------
__global__ __launch_bounds__(256) void gather64(const float* __restrict__ h,
        const int* __restrict__ adj, const int* __restrict__ end_, const int* __restrict__ deg,
        float* __restrict__ agg) {
    int wid = (blockIdx.x * blockDim.x + threadIdx.x) >> 6;
    int lane = threadIdx.x & 63;
    if (wid >= N_NODES) return;
    int e = end_[wid];
    int d = deg[wid];
    int s = e - d;
    float acc = 0.0f;
    for (int base = 0; base < d; base += 64) {
        int chunk = min(64, d - base);
        int myadj = (base + lane < d) ? adj[s + base + lane] : 0;
        int j = 0;
        for (; j + 4 <= chunk; j += 4) {
            int s0 = __shfl(myadj, j);
            int s1 = __shfl(myadj, j + 1);
            int s2 = __shfl(myadj, j + 2);
            int s3 = __shfl(myadj, j + 3);
            float v0 = h[(size_t)s0 * 64 + lane];
            float v1 = h[(size_t)s1 * 64 + lane];
            float v2 = h[(size_t)s2 * 64 + lane];
            float v3 = h[(size_t)s3 * 64 + lane];
            acc += v0 + v1 + v2 + v3;
        }
        for (; j < chunk; ++j) {
            int sn = __shfl(myadj, j);
            acc += h[(size_t)sn * 64 + lane];
        }
    }
    agg[(size_t)wid * 64 + lane] = acc;
}

__global__ __launch_bounds__(256) void gather32(const float* __restrict__ xin,
        const int* __restrict__ adj, const int* __restrict__ end_, const int* __restrict__ deg,
        float* __restrict__ agg) {
    int wid = (blockIdx.x * blockDim.x + threadIdx.x) >> 6;
    int lane = threadIdx.x & 63;
    int hw = lane >> 5;
    int f = lane & 31;
    int node = wid * 2 + hw;
    if (node >= N_NODES) return;
    int e = end_[node];
    int d = deg[node];
    int s = e - d;
    float acc = 0.0f;
    for (int base = 0; base < d; base += 32) {
        int chunk = min(32, d - base);
        int myadj = (base + f < d) ? adj[s + base + f] : 0;
        int j = 0;
        for (; j + 4 <= chunk; j += 4) {
            int s0 = __shfl(myadj, hw * 32 + j);
            int s1 = __shfl(myadj, hw * 32 + j + 1);
            int s2 = __shfl(myadj, hw * 32 + j + 2);
            int s3 = __shfl(myadj, hw * 32 + j + 3);
            float v0 = xin[(size_t)s0 * 32 + f];
            float v1 = xin[(size_t)s1 * 32 + f];
            float v2 = xin[(size_t)s2 * 32 + f];
            float v3 = xin[(size_t)s3 * 32 + f];
            acc += v0 + v1 + v2 + v3;
        }
        for (; j < chunk; ++j) {
            int sn = __shfl(myadj, hw * 32 + j);
            acc += xin[(size_t)sn * 32 + f];
        }
    }
    agg[(size_t)node * 32 + f] = acc;
}

// ---------------- register-resident transforms (no LDS) ----------------
// One wave owns a contiguous node range; lane fo holds weight columns
// Wrel[:,fo], Wroot[:,fo] in registers (fully unrolled static indexing).
// Per node: wave-uniform float4 row loads (L2-resident broadcast) + register FMAs.
__global__ __launch_bounds__(256) void transform1_reg(const float* __restrict__ agg,
        const float* __restrict__ xin,
        const float* __restrict__ Wrel, const float* __restrict__ brel,
        const float* __restrict__ Wroot,
        float* __restrict__ h1) {
    int lane = threadIdx.x & 63;
    int wgid = __builtin_amdgcn_readfirstlane(blockIdx.x * 4 + (threadIdx.x >> 6));
    int n0 = wgid * NODES_PER_WAVE;
    if (n0 >= N_NODES) return;
    int n1 = min(n0 + NODES_PER_WAVE, N_NODES);

    float wrel[32], wroot[32];
#pragma unroll
    for (int k = 0; k < 32; ++k) {
        wrel[k] = Wrel[k * 64 + lane];     // coalesced: lanes read consecutive floats
        wroot[k] = Wroot[k * 64 + lane];
    }
    float b = brel[lane];

    for (int node = n0; node < n1; ++node) {
        const float4* ar = (const float4*)(agg + (size_t)node * 32);
        const float4* xr = (const float4*)(xin + (size_t)node * 32);
        float o = b;
#pragma unroll
        for (int kk = 0; kk < 8; ++kk) {
            float4 a4 = ar[kk];
            float4 x4 = xr[kk];
            o += a4.x * wrel[kk * 4 + 0] + a4.y * wrel[kk * 4 + 1]
               + a4.z * wrel[kk * 4 + 2] + a4.w * wrel[kk * 4 + 3];
            o += x4.x * wroot[kk * 4 + 0] + x4.y * wroot[kk * 4 + 1]
               + x4.z * wroot[kk * 4 + 2] + x4.w * wroot[kk * 4 + 3];
        }
        h1[(size_t)node * 64 + lane] = tanhf(o);
    }
}

// Layer 2 + pooling: batch is sorted and node ranges are contiguous, so keep a
// register pool-accumulator and flush to global atomics only on graph change.
__global__ __launch_bounds__(256) void transform2_pool_reg(const float* __restrict__ agg,
        const float* __restrict__ h1,
        const float* __restrict__ Wrel, const float* __restrict__ brel,
        const float* __restrict__ Wroot,
        const int* __restrict__ batch,
        float* __restrict__ sums) {
    int lane = threadIdx.x & 63;
    int wgid = __builtin_amdgcn_readfirstlane(blockIdx.x * 4 + (threadIdx.x >> 6));
    int n0 = wgid * NODES_PER_WAVE;
    if (n0 >= N_NODES) return;
    int n1 = min(n0 + NODES_PER_WAVE, N_NODES);

    float wrel[64], wroot[64];
#pragma unroll
    for (int k = 0; k < 64; ++k) {
        wrel[k] = Wrel[k * 64 + lane];
        wroot[k] = Wroot[k * 64 + lane];
    }
    float b = brel[lane];

    float psum = 0.0f;
    int curg = batch[n0];                    // wave-uniform
    for (int node = n0; node < n1; ++node) {
        const float4* ar = (const float4*)(agg + (size_t)node * 64);
        const float4* xr = (const float4*)(h1 + (size_t)node * 64);
        float o = b;
#pragma unroll
        for (int kk = 0; kk < 16; ++kk) {
            float4 a4 = ar[kk];
            float4 x4 = xr[kk];
            o += a4.x * wrel[kk * 4 + 0] + a4.y * wrel[kk * 4 + 1]
               + a4.z * wrel[kk * 4 + 2] + a4.w * wrel[kk * 4 + 3];
            o += x4.x * wroot[kk * 4 + 0] + x4.y * wroot[kk * 4 + 1]
               + x4.z * wroot[kk * 4 + 2] + x4.w * wroot[kk * 4 + 3];
        }
        float h2 = tanhf(o);
        int g = batch[node];                 // wave-uniform
        if (g != curg) {                     // wave-uniform branch
            atomicAdd(&sums[(size_t)curg * 64 + lane], psum);
            psum = 0.0f;
            curg = g;
        }
        psum += h2;
    }
    atomicAdd(&sums[(size_t)curg * 64 + lane], psum);
}

// counts[g] via binary search over the SORTED batch array
__global__ void graph_counts(const int* __restrict__ batch, float* __restrict__ counts) {
    int g = threadIdx.x;
    if (g >= N_GRAPHS) return;
    int lo = 0, hi = N_NODES;
    while (lo < hi) { int mid = (lo + hi) >> 1; if (batch[mid] < g) lo = mid + 1; else hi = mid; }
    int start = lo;
    lo = 0; hi = N_NODES;
    while (lo < hi) { int mid = (lo + hi) >> 1; if (batch[mid] <= g) lo = mid + 1; else hi = mid; }
    counts[g] = (float)(lo - start);
}

__global__ void finalize(const float* __restrict__ sums,
                         const float* __restrict__ counts,
                         float* __restrict__ out) {
    int i = blockIdx.x * blockDim.x + threadIdx.x;
    if (i < N_GRAPHS * 64) {
        float c = counts[i >> 6];
        out[i] = sums[i] / fmaxf(c, 1.0f);
    }
}

extern "C" void kernel_launch(void* const* d_in, const int* in_sizes, int n_in,
                              void* d_out, int out_size, void* d_ws, size_t ws_size,
                              hipStream_t stream) {
    const float* x       = (const float*)d_in[0];
    const int*   ei      = (const int*)d_in[1];
    const int*   batch   = (const int*)d_in[2];
    const float* W1_rel  = (const float*)d_in[3];
    const float* b1_rel  = (const float*)d_in[4];
    const float* W1_root = (const float*)d_in[5];
    const float* W2_rel  = (const float*)d_in[6];
    const float* b2_rel  = (const float*)d_in[7];
    const float* W2_root = (const float*)d_in[8];
    float* out = (float*)d_out;

    const int* src = ei;
    const int* dst = ei + N_EDGES;

    // ---- workspace layout (bytes) ----
    char* ws = (char*)d_ws;
    int*   deg      = (int*)(ws + 0);                 // 400000
    float* sums     = (float*)(ws + 400000);          // 65536
    float* counts   = (float*)(ws + 465536);          // 1024
    // ---- zero boundary: 466560 ----
    int*   end_     = (int*)(ws + 466560);            // 400000
    int*   cursor   = (int*)(ws + 866560);            // 400000
    int*   partials = (int*)(ws + 1266560);           // 2048
    int*   adj      = (int*)(ws + 1268608);           // 6400000
    float* aggbuf   = (float*)(ws + 7668608);         // 25600000 (agg1/agg2 shared)
    float* h1       = (float*)(ws + 33268608);        // 25600000

    hipMemsetAsync(d_ws, 0, 466560, stream);

    // ---- CSR build ----
    const int NB_NODE = (N_NODES + 255) / 256;
    histogram_dst<<<(N_EDGES + 255) / 256, 256, 0, stream>>>(dst, deg);
    scan1<<<NB_NODE, 256, 0, stream>>>(deg, end_, partials);
    scan2<<<1, 512, 0, stream>>>(partials, NB_NODE);
    scan3<<<NB_NODE, 256, 0, stream>>>(deg, end_, cursor, partials);
    fill_adj<<<(N_EDGES + 255) / 256, 256, 0, stream>>>(src, dst, cursor, adj);

    // ---- layer 1 ----
    gather32<<<((N_NODES + 1) / 2 * 64 + 255) / 256, 256, 0, stream>>>(x, adj, end_, deg, aggbuf);
    transform1_reg<<<T_WAVES / 4, 256, 0, stream>>>(aggbuf, x, W1_rel, b1_rel, W1_root, h1);

    // ---- layer 2 ----
    gather64<<<(N_NODES * 64 + 255) / 256, 256, 0, stream>>>(h1, adj, end_, deg, aggbuf);
    transform2_pool_reg<<<T_WAVES / 4, 256, 0, stream>>>(aggbuf, h1, W2_rel, b2_rel, W2_root, batch, sums);

    graph_counts<<<1, 256, 0, stream>>>(batch, counts);
    finalize<<<(N_GRAPHS * 64 + 255) / 256, 256, 0, stream>>>(sums, counts, out);
}

// Round 8
// 413.656 us; speedup vs baseline: 6.0465x; 1.0428x over previous
//
#include <hip/hip_runtime.h>

#define N_NODES 100000
#define N_EDGES 1600000
#define N_GRAPHS 256
#define F_IN 32
#define F_HID 64
#define F_OUT 64

#define T_WAVES 2048
#define NODES_PER_WAVE ((N_NODES + T_WAVES - 1) / T_WAVES)   // 49
#define FILL_PASS_SHIFT 14
#define FILL_NPASS ((N_NODES + (1 << FILL_PASS_SHIFT) - 1) >> FILL_PASS_SHIFT)  // 7

// ---------------- CSR build ----------------
__global__ void histogram_dst(const int* __restrict__ dst, int* __restrict__ deg) {
    int e = blockIdx.x * blockDim.x + threadIdx.x;
    if (e < N_EDGES) atomicAdd(&deg[dst[e]], 1);
}

__global__ void scan1(const int* __restrict__ deg, int* __restrict__ end_, int* __restrict__ partials) {
    __shared__ int s[256];
    int tid = threadIdx.x;
    int i = blockIdx.x * 256 + tid;
    int v = (i < N_NODES) ? deg[i] : 0;
    s[tid] = v;
    __syncthreads();
#pragma unroll
    for (int off = 1; off < 256; off <<= 1) {
        int t = 0;
        if (tid >= off) t = s[tid - off];
        __syncthreads();
        if (tid >= off) s[tid] += t;
        __syncthreads();
    }
    if (i < N_NODES) end_[i] = s[tid];
    if (tid == 255) partials[blockIdx.x] = s[255];
}

__global__ void scan2(int* __restrict__ partials, int nb) {
    __shared__ int s[512];
    int tid = threadIdx.x;
    int v = (tid < nb) ? partials[tid] : 0;
    s[tid] = v;
    __syncthreads();
#pragma unroll
    for (int off = 1; off < 512; off <<= 1) {
        int t = 0;
        if (tid >= off) t = s[tid - off];
        __syncthreads();
        if (tid >= off) s[tid] += t;
        __syncthreads();
    }
    int excl = (tid > 0) ? s[tid - 1] : 0;
    if (tid < nb) partials[tid] = excl;
}

__global__ void scan3(const int* __restrict__ deg, int* __restrict__ end_,
                      int* __restrict__ cursor, const int* __restrict__ partials) {
    int i = blockIdx.x * 256 + threadIdx.x;
    if (i < N_NODES) {
        int e = end_[i] + partials[blockIdx.x];
        end_[i] = e;
        cursor[i] = e - deg[i];
    }
}

// Multi-pass fill: pass p handles dst in [p*16384, (p+1)*16384).
// Active adj region per pass (~0.9 MB) stays L2-resident so lines fill
// completely before writeback (105 MB -> ~6.4 MB HBM write traffic).
__global__ __launch_bounds__(256) void fill_adj_mp(const int* __restrict__ src,
                                                   const int* __restrict__ dst,
                                                   int* __restrict__ cursor,
                                                   int* __restrict__ adj) {
    int gid = blockIdx.x * blockDim.x + threadIdx.x;
    int stride = gridDim.x * blockDim.x;
    for (int p = 0; p < FILL_NPASS; ++p) {
        for (int e = gid; e < N_EDGES; e += stride) {
            int d = dst[e];
            if ((d >> FILL_PASS_SHIFT) == p) {
                int pos = atomicAdd(&cursor[d], 1);
                adj[pos] = src[e];
            }
        }
    }
}

// ---------------- float4 gathers ----------------
// gather64: wave per node; lane = slot r (lane>>4) x quad q (lane&15).
// One float4 load instruction covers 4 neighbor rows (64 lanes x 16B = 4 x 256B rows).
__global__ __launch_bounds__(256) void gather64_v2(const float* __restrict__ h,
        const int* __restrict__ adj, const int* __restrict__ end_, const int* __restrict__ deg,
        float* __restrict__ agg) {
    int node = (blockIdx.x * blockDim.x + threadIdx.x) >> 6;
    int lane = threadIdx.x & 63;
    if (node >= N_NODES) return;
    int e = end_[node];
    int d = deg[node];
    int s = e - d;
    int q = lane & 15;
    int r = lane >> 4;
    const float4* h4 = (const float4*)h;

    float ax = 0.f, ay = 0.f, az = 0.f, aw = 0.f;
    for (int base = 0; base < d; base += 8) {
        int i0 = base + r;
        int i1 = base + 4 + r;
        if (i0 < d) {
            int s0 = adj[s + i0];
            float4 v = h4[(size_t)s0 * 16 + q];
            ax += v.x; ay += v.y; az += v.z; aw += v.w;
        }
        if (i1 < d) {
            int s1 = adj[s + i1];
            float4 v = h4[(size_t)s1 * 16 + q];
            ax += v.x; ay += v.y; az += v.z; aw += v.w;
        }
    }
    // reduce across the 4 slot groups (lanes q, q+16, q+32, q+48)
#pragma unroll
    for (int off = 16; off < 64; off <<= 1) {
        ax += __shfl_xor(ax, off);
        ay += __shfl_xor(ay, off);
        az += __shfl_xor(az, off);
        aw += __shfl_xor(aw, off);
    }
    if (r == 0) {
        float4 o; o.x = ax; o.y = ay; o.z = az; o.w = aw;
        ((float4*)agg)[(size_t)node * 16 + q] = o;
    }
}

// gather32: wave per node; lane = slot r (lane>>3) x quad q (lane&7).
// One float4 load instruction covers 8 neighbor rows (64 x 16B = 8 x 128B rows).
__global__ __launch_bounds__(256) void gather32_v2(const float* __restrict__ xin,
        const int* __restrict__ adj, const int* __restrict__ end_, const int* __restrict__ deg,
        float* __restrict__ agg) {
    int node = (blockIdx.x * blockDim.x + threadIdx.x) >> 6;
    int lane = threadIdx.x & 63;
    if (node >= N_NODES) return;
    int e = end_[node];
    int d = deg[node];
    int s = e - d;
    int q = lane & 7;
    int r = lane >> 3;
    const float4* x4 = (const float4*)xin;

    float ax = 0.f, ay = 0.f, az = 0.f, aw = 0.f;
    for (int base = 0; base < d; base += 16) {
        int i0 = base + r;
        int i1 = base + 8 + r;
        if (i0 < d) {
            int s0 = adj[s + i0];
            float4 v = x4[(size_t)s0 * 8 + q];
            ax += v.x; ay += v.y; az += v.z; aw += v.w;
        }
        if (i1 < d) {
            int s1 = adj[s + i1];
            float4 v = x4[(size_t)s1 * 8 + q];
            ax += v.x; ay += v.y; az += v.z; aw += v.w;
        }
    }
#pragma unroll
    for (int off = 8; off < 64; off <<= 1) {
        ax += __shfl_xor(ax, off);
        ay += __shfl_xor(ay, off);
        az += __shfl_xor(az, off);
        aw += __shfl_xor(aw, off);
    }
    if (r == 0) {
        float4 o; o.x = ax; o.y = ay; o.z = az; o.w = aw;
        ((float4*)agg)[(size_t)node * 8 + q] = o;
    }
}

// ---------------- register-resident transforms (no LDS) ----------------
__global__ __launch_bounds__(256) void transform1_reg(const float* __restrict__ agg,
        const float* __restrict__ xin,
        const float* __restrict__ Wrel, const float* __restrict__ brel,
        const float* __restrict__ Wroot,
        float* __restrict__ h1) {
    int lane = threadIdx.x & 63;
    int wgid = __builtin_amdgcn_readfirstlane(blockIdx.x * 4 + (threadIdx.x >> 6));
    int n0 = wgid * NODES_PER_WAVE;
    if (n0 >= N_NODES) return;
    int n1 = min(n0 + NODES_PER_WAVE, N_NODES);

    float wrel[32], wroot[32];
#pragma unroll
    for (int k = 0; k < 32; ++k) {
        wrel[k] = Wrel[k * 64 + lane];
        wroot[k] = Wroot[k * 64 + lane];
    }
    float b = brel[lane];

    for (int node = n0; node < n1; ++node) {
        const float4* ar = (const float4*)(agg + (size_t)node * 32);
        const float4* xr = (const float4*)(xin + (size_t)node * 32);
        float o = b;
#pragma unroll
        for (int kk = 0; kk < 8; ++kk) {
            float4 a4 = ar[kk];
            float4 x4 = xr[kk];
            o += a4.x * wrel[kk * 4 + 0] + a4.y * wrel[kk * 4 + 1]
               + a4.z * wrel[kk * 4 + 2] + a4.w * wrel[kk * 4 + 3];
            o += x4.x * wroot[kk * 4 + 0] + x4.y * wroot[kk * 4 + 1]
               + x4.z * wroot[kk * 4 + 2] + x4.w * wroot[kk * 4 + 3];
        }
        h1[(size_t)node * 64 + lane] = tanhf(o);
    }
}

__global__ __launch_bounds__(256) void transform2_pool_reg(const float* __restrict__ agg,
        const float* __restrict__ h1,
        const float* __restrict__ Wrel, const float* __restrict__ brel,
        const float* __restrict__ Wroot,
        const int* __restrict__ batch,
        float* __restrict__ sums) {
    int lane = threadIdx.x & 63;
    int wgid = __builtin_amdgcn_readfirstlane(blockIdx.x * 4 + (threadIdx.x >> 6));
    int n0 = wgid * NODES_PER_WAVE;
    if (n0 >= N_NODES) return;
    int n1 = min(n0 + NODES_PER_WAVE, N_NODES);

    float wrel[64], wroot[64];
#pragma unroll
    for (int k = 0; k < 64; ++k) {
        wrel[k] = Wrel[k * 64 + lane];
        wroot[k] = Wroot[k * 64 + lane];
    }
    float b = brel[lane];

    float psum = 0.0f;
    int curg = batch[n0];
    for (int node = n0; node < n1; ++node) {
        const float4* ar = (const float4*)(agg + (size_t)node * 64);
        const float4* xr = (const float4*)(h1 + (size_t)node * 64);
        float o = b;
#pragma unroll
        for (int kk = 0; kk < 16; ++kk) {
            float4 a4 = ar[kk];
            float4 x4 = xr[kk];
            o += a4.x * wrel[kk * 4 + 0] + a4.y * wrel[kk * 4 + 1]
               + a4.z * wrel[kk * 4 + 2] + a4.w * wrel[kk * 4 + 3];
            o += x4.x * wroot[kk * 4 + 0] + x4.y * wroot[kk * 4 + 1]
               + x4.z * wroot[kk * 4 + 2] + x4.w * wroot[kk * 4 + 3];
        }
        float h2 = tanhf(o);
        int g = batch[node];
        if (g != curg) {
            atomicAdd(&sums[(size_t)curg * 64 + lane], psum);
            psum = 0.0f;
            curg = g;
        }
        psum += h2;
    }
    atomicAdd(&sums[(size_t)curg * 64 + lane], psum);
}

__global__ void graph_counts(const int* __restrict__ batch, float* __restrict__ counts) {
    int g = threadIdx.x;
    if (g >= N_GRAPHS) return;
    int lo = 0, hi = N_NODES;
    while (lo < hi) { int mid = (lo + hi) >> 1; if (batch[mid] < g) lo = mid + 1; else hi = mid; }
    int start = lo;
    lo = 0; hi = N_NODES;
    while (lo < hi) { int mid = (lo + hi) >> 1; if (batch[mid] <= g) lo = mid + 1; else hi = mid; }
    counts[g] = (float)(lo - start);
}

__global__ void finalize(const float* __restrict__ sums,
                         const float* __restrict__ counts,
                         float* __restrict__ out) {
    int i = blockIdx.x * blockDim.x + threadIdx.x;
    if (i < N_GRAPHS * 64) {
        float c = counts[i >> 6];
        out[i] = sums[i] / fmaxf(c, 1.0f);
    }
}

extern "C" void kernel_launch(void* const* d_in, const int* in_sizes, int n_in,
                              void* d_out, int out_size, void* d_ws, size_t ws_size,
                              hipStream_t stream) {
    const float* x       = (const float*)d_in[0];
    const int*   ei      = (const int*)d_in[1];
    const int*   batch   = (const int*)d_in[2];
    const float* W1_rel  = (const float*)d_in[3];
    const float* b1_rel  = (const float*)d_in[4];
    const float* W1_root = (const float*)d_in[5];
    const float* W2_rel  = (const float*)d_in[6];
    const float* b2_rel  = (const float*)d_in[7];
    const float* W2_root = (const float*)d_in[8];
    float* out = (float*)d_out;

    const int* src = ei;
    const int* dst = ei + N_EDGES;

    // ---- workspace layout (bytes) ----
    char* ws = (char*)d_ws;
    int*   deg      = (int*)(ws + 0);                 // 400000
    float* sums     = (float*)(ws + 400000);          // 65536
    float* counts   = (float*)(ws + 465536);          // 1024
    // ---- zero boundary: 466560 ----
    int*   end_     = (int*)(ws + 466560);            // 400000
    int*   cursor   = (int*)(ws + 866560);            // 400000
    int*   partials = (int*)(ws + 1266560);           // 2048
    int*   adj      = (int*)(ws + 1268608);           // 6400000
    float* aggbuf   = (float*)(ws + 7668608);         // 25600000 (agg1/agg2 shared)
    float* h1       = (float*)(ws + 33268608);        // 25600000

    hipMemsetAsync(d_ws, 0, 466560, stream);

    // ---- CSR build ----
    const int NB_NODE = (N_NODES + 255) / 256;
    histogram_dst<<<(N_EDGES + 255) / 256, 256, 0, stream>>>(dst, deg);
    scan1<<<NB_NODE, 256, 0, stream>>>(deg, end_, partials);
    scan2<<<1, 512, 0, stream>>>(partials, NB_NODE);
    scan3<<<NB_NODE, 256, 0, stream>>>(deg, end_, cursor, partials);
    fill_adj_mp<<<2048, 256, 0, stream>>>(src, dst, cursor, adj);

    // ---- layer 1 ----
    gather32_v2<<<(N_NODES * 64 + 255) / 256, 256, 0, stream>>>(x, adj, end_, deg, aggbuf);
    transform1_reg<<<T_WAVES / 4, 256, 0, stream>>>(aggbuf, x, W1_rel, b1_rel, W1_root, h1);

    // ---- layer 2 ----
    gather64_v2<<<(N_NODES * 64 + 255) / 256, 256, 0, stream>>>(h1, adj, end_, deg, aggbuf);
    transform2_pool_reg<<<T_WAVES / 4, 256, 0, stream>>>(aggbuf, h1, W2_rel, b2_rel, W2_root, batch, sums);

    graph_counts<<<1, 256, 0, stream>>>(batch, counts);
    finalize<<<(N_GRAPHS * 64 + 255) / 256, 256, 0, stream>>>(sums, counts, out);
}

// Round 9
// 384.797 us; speedup vs baseline: 6.5000x; 1.0750x over previous
//
#include <hip/hip_runtime.h>

#define N_NODES 100000
#define N_EDGES 1600000
#define N_GRAPHS 256
#define F_IN 32
#define F_HID 64
#define F_OUT 64

#define T_WAVES 8192            // 2048 blocks x 4 waves; ~8 blocks/CU -> high occupancy
#define NODES_PER_WAVE ((N_NODES + T_WAVES - 1) / T_WAVES)   // 13
#define FILL_PASS_SHIFT 14
#define FILL_NPASS ((N_NODES + (1 << FILL_PASS_SHIFT) - 1) >> FILL_PASS_SHIFT)  // 7

// ---------------- CSR build ----------------
__global__ void histogram_dst(const int* __restrict__ dst, int* __restrict__ deg) {
    int e = blockIdx.x * blockDim.x + threadIdx.x;
    if (e < N_EDGES) atomicAdd(&deg[dst[e]], 1);
}

__global__ void scan1(const int* __restrict__ deg, int* __restrict__ end_, int* __restrict__ partials) {
    __shared__ int s[256];
    int tid = threadIdx.x;
    int i = blockIdx.x * 256 + tid;
    int v = (i < N_NODES) ? deg[i] : 0;
    s[tid] = v;
    __syncthreads();
#pragma unroll
    for (int off = 1; off < 256; off <<= 1) {
        int t = 0;
        if (tid >= off) t = s[tid - off];
        __syncthreads();
        if (tid >= off) s[tid] += t;
        __syncthreads();
    }
    if (i < N_NODES) end_[i] = s[tid];
    if (tid == 255) partials[blockIdx.x] = s[255];
}

__global__ void scan2(int* __restrict__ partials, int nb) {
    __shared__ int s[512];
    int tid = threadIdx.x;
    int v = (tid < nb) ? partials[tid] : 0;
    s[tid] = v;
    __syncthreads();
#pragma unroll
    for (int off = 1; off < 512; off <<= 1) {
        int t = 0;
        if (tid >= off) t = s[tid - off];
        __syncthreads();
        if (tid >= off) s[tid] += t;
        __syncthreads();
    }
    int excl = (tid > 0) ? s[tid - 1] : 0;
    if (tid < nb) partials[tid] = excl;
}

__global__ void scan3(const int* __restrict__ deg, int* __restrict__ end_,
                      int* __restrict__ cursor, const int* __restrict__ partials) {
    int i = blockIdx.x * 256 + threadIdx.x;
    if (i < N_NODES) {
        int e = end_[i] + partials[blockIdx.x];
        end_[i] = e;
        cursor[i] = e - deg[i];
    }
}

// Multi-pass fill keeps the active adj window L2-resident (dense-line writeback).
__global__ __launch_bounds__(256) void fill_adj_mp(const int* __restrict__ src,
                                                   const int* __restrict__ dst,
                                                   int* __restrict__ cursor,
                                                   int* __restrict__ adj) {
    int gid = blockIdx.x * blockDim.x + threadIdx.x;
    int stride = gridDim.x * blockDim.x;
    for (int p = 0; p < FILL_NPASS; ++p) {
        for (int e = gid; e < N_EDGES; e += stride) {
            int d = dst[e];
            if ((d >> FILL_PASS_SHIFT) == p) {
                int pos = atomicAdd(&cursor[d], 1);
                adj[pos] = src[e];
            }
        }
    }
}

// ---------------- float4 gathers ----------------
__global__ __launch_bounds__(256) void gather64_v2(const float* __restrict__ h,
        const int* __restrict__ adj, const int* __restrict__ end_, const int* __restrict__ deg,
        float* __restrict__ agg) {
    int node = (blockIdx.x * blockDim.x + threadIdx.x) >> 6;
    int lane = threadIdx.x & 63;
    if (node >= N_NODES) return;
    int e = end_[node];
    int d = deg[node];
    int s = e - d;
    int q = lane & 15;
    int r = lane >> 4;
    const float4* h4 = (const float4*)h;

    float ax = 0.f, ay = 0.f, az = 0.f, aw = 0.f;
    for (int base = 0; base < d; base += 8) {
        int i0 = base + r;
        int i1 = base + 4 + r;
        if (i0 < d) {
            int s0 = adj[s + i0];
            float4 v = h4[(size_t)s0 * 16 + q];
            ax += v.x; ay += v.y; az += v.z; aw += v.w;
        }
        if (i1 < d) {
            int s1 = adj[s + i1];
            float4 v = h4[(size_t)s1 * 16 + q];
            ax += v.x; ay += v.y; az += v.z; aw += v.w;
        }
    }
#pragma unroll
    for (int off = 16; off < 64; off <<= 1) {
        ax += __shfl_xor(ax, off);
        ay += __shfl_xor(ay, off);
        az += __shfl_xor(az, off);
        aw += __shfl_xor(aw, off);
    }
    if (r == 0) {
        float4 o; o.x = ax; o.y = ay; o.z = az; o.w = aw;
        ((float4*)agg)[(size_t)node * 16 + q] = o;
    }
}

__global__ __launch_bounds__(256) void gather32_v2(const float* __restrict__ xin,
        const int* __restrict__ adj, const int* __restrict__ end_, const int* __restrict__ deg,
        float* __restrict__ agg) {
    int node = (blockIdx.x * blockDim.x + threadIdx.x) >> 6;
    int lane = threadIdx.x & 63;
    if (node >= N_NODES) return;
    int e = end_[node];
    int d = deg[node];
    int s = e - d;
    int q = lane & 7;
    int r = lane >> 3;
    const float4* x4 = (const float4*)xin;

    float ax = 0.f, ay = 0.f, az = 0.f, aw = 0.f;
    for (int base = 0; base < d; base += 16) {
        int i0 = base + r;
        int i1 = base + 8 + r;
        if (i0 < d) {
            int s0 = adj[s + i0];
            float4 v = x4[(size_t)s0 * 8 + q];
            ax += v.x; ay += v.y; az += v.z; aw += v.w;
        }
        if (i1 < d) {
            int s1 = adj[s + i1];
            float4 v = x4[(size_t)s1 * 8 + q];
            ax += v.x; ay += v.y; az += v.z; aw += v.w;
        }
    }
#pragma unroll
    for (int off = 8; off < 64; off <<= 1) {
        ax += __shfl_xor(ax, off);
        ay += __shfl_xor(ay, off);
        az += __shfl_xor(az, off);
        aw += __shfl_xor(aw, off);
    }
    if (r == 0) {
        float4 o; o.x = ax; o.y = ay; o.z = az; o.w = aw;
        ((float4*)agg)[(size_t)node * 8 + q] = o;
    }
}

// ---------------- register-resident transforms (no LDS) ----------------
__global__ __launch_bounds__(256) void transform1_reg(const float* __restrict__ agg,
        const float* __restrict__ xin,
        const float* __restrict__ Wrel, const float* __restrict__ brel,
        const float* __restrict__ Wroot,
        float* __restrict__ h1) {
    int lane = threadIdx.x & 63;
    int wgid = __builtin_amdgcn_readfirstlane(blockIdx.x * 4 + (threadIdx.x >> 6));
    int n0 = wgid * NODES_PER_WAVE;
    if (n0 >= N_NODES) return;
    int n1 = min(n0 + NODES_PER_WAVE, N_NODES);

    float wrel[32], wroot[32];
#pragma unroll
    for (int k = 0; k < 32; ++k) {
        wrel[k] = Wrel[k * 64 + lane];
        wroot[k] = Wroot[k * 64 + lane];
    }
    float b = brel[lane];

    for (int node = n0; node < n1; ++node) {
        const float4* ar = (const float4*)(agg + (size_t)node * 32);
        const float4* xr = (const float4*)(xin + (size_t)node * 32);
        float o = b;
#pragma unroll
        for (int kk = 0; kk < 8; ++kk) {
            float4 a4 = ar[kk];
            float4 x4 = xr[kk];
            o += a4.x * wrel[kk * 4 + 0] + a4.y * wrel[kk * 4 + 1]
               + a4.z * wrel[kk * 4 + 2] + a4.w * wrel[kk * 4 + 3];
            o += x4.x * wroot[kk * 4 + 0] + x4.y * wroot[kk * 4 + 1]
               + x4.z * wroot[kk * 4 + 2] + x4.w * wroot[kk * 4 + 3];
        }
        h1[(size_t)node * 64 + lane] = tanhf(o);
    }
}

__global__ __launch_bounds__(256) void transform2_pool_reg(const float* __restrict__ agg,
        const float* __restrict__ h1,
        const float* __restrict__ Wrel, const float* __restrict__ brel,
        const float* __restrict__ Wroot,
        const int* __restrict__ batch,
        float* __restrict__ sums) {
    int lane = threadIdx.x & 63;
    int wgid = __builtin_amdgcn_readfirstlane(blockIdx.x * 4 + (threadIdx.x >> 6));
    int n0 = wgid * NODES_PER_WAVE;
    if (n0 >= N_NODES) return;
    int n1 = min(n0 + NODES_PER_WAVE, N_NODES);

    float wrel[64], wroot[64];
#pragma unroll
    for (int k = 0; k < 64; ++k) {
        wrel[k] = Wrel[k * 64 + lane];
        wroot[k] = Wroot[k * 64 + lane];
    }
    float b = brel[lane];

    float psum = 0.0f;
    int curg = batch[n0];
    for (int node = n0; node < n1; ++node) {
        const float4* ar = (const float4*)(agg + (size_t)node * 64);
        const float4* xr = (const float4*)(h1 + (size_t)node * 64);
        float o = b;
#pragma unroll
        for (int kk = 0; kk < 16; ++kk) {
            float4 a4 = ar[kk];
            float4 x4 = xr[kk];
            o += a4.x * wrel[kk * 4 + 0] + a4.y * wrel[kk * 4 + 1]
               + a4.z * wrel[kk * 4 + 2] + a4.w * wrel[kk * 4 + 3];
            o += x4.x * wroot[kk * 4 + 0] + x4.y * wroot[kk * 4 + 1]
               + x4.z * wroot[kk * 4 + 2] + x4.w * wroot[kk * 4 + 3];
        }
        float h2 = tanhf(o);
        int g = batch[node];
        if (g != curg) {
            atomicAdd(&sums[(size_t)curg * 64 + lane], psum);
            psum = 0.0f;
            curg = g;
        }
        psum += h2;
    }
    atomicAdd(&sums[(size_t)curg * 64 + lane], psum);
}

__global__ void graph_counts(const int* __restrict__ batch, float* __restrict__ counts) {
    int g = threadIdx.x;
    if (g >= N_GRAPHS) return;
    int lo = 0, hi = N_NODES;
    while (lo < hi) { int mid = (lo + hi) >> 1; if (batch[mid] < g) lo = mid + 1; else hi = mid; }
    int start = lo;
    lo = 0; hi = N_NODES;
    while (lo < hi) { int mid = (lo + hi) >> 1; if (batch[mid] <= g) lo = mid + 1; else hi = mid; }
    counts[g] = (float)(lo - start);
}

__global__ void finalize(const float* __restrict__ sums,
                         const float* __restrict__ counts,
                         float* __restrict__ out) {
    int i = blockIdx.x * blockDim.x + threadIdx.x;
    if (i < N_GRAPHS * 64) {
        float c = counts[i >> 6];
        out[i] = sums[i] / fmaxf(c, 1.0f);
    }
}

extern "C" void kernel_launch(void* const* d_in, const int* in_sizes, int n_in,
                              void* d_out, int out_size, void* d_ws, size_t ws_size,
                              hipStream_t stream) {
    const float* x       = (const float*)d_in[0];
    const int*   ei      = (const int*)d_in[1];
    const int*   batch   = (const int*)d_in[2];
    const float* W1_rel  = (const float*)d_in[3];
    const float* b1_rel  = (const float*)d_in[4];
    const float* W1_root = (const float*)d_in[5];
    const float* W2_rel  = (const float*)d_in[6];
    const float* b2_rel  = (const float*)d_in[7];
    const float* W2_root = (const float*)d_in[8];
    float* out = (float*)d_out;

    const int* src = ei;
    const int* dst = ei + N_EDGES;

    // ---- workspace layout (bytes) ----
    char* ws = (char*)d_ws;
    int*   deg      = (int*)(ws + 0);                 // 400000
    float* sums     = (float*)(ws + 400000);          // 65536
    float* counts   = (float*)(ws + 465536);          // 1024
    // ---- zero boundary: 466560 ----
    int*   end_     = (int*)(ws + 466560);            // 400000
    int*   cursor   = (int*)(ws + 866560);            // 400000
    int*   partials = (int*)(ws + 1266560);           // 2048
    int*   adj      = (int*)(ws + 1268608);           // 6400000
    float* aggbuf   = (float*)(ws + 7668608);         // 25600000 (agg1/agg2 shared)
    float* h1       = (float*)(ws + 33268608);        // 25600000

    hipMemsetAsync(d_ws, 0, 466560, stream);

    // ---- CSR build ----
    const int NB_NODE = (N_NODES + 255) / 256;
    histogram_dst<<<(N_EDGES + 255) / 256, 256, 0, stream>>>(dst, deg);
    scan1<<<NB_NODE, 256, 0, stream>>>(deg, end_, partials);
    scan2<<<1, 512, 0, stream>>>(partials, NB_NODE);
    scan3<<<NB_NODE, 256, 0, stream>>>(deg, end_, cursor, partials);
    fill_adj_mp<<<2048, 256, 0, stream>>>(src, dst, cursor, adj);

    // ---- layer 1 ----
    gather32_v2<<<(N_NODES * 64 + 255) / 256, 256, 0, stream>>>(x, adj, end_, deg, aggbuf);
    transform1_reg<<<T_WAVES / 4, 256, 0, stream>>>(aggbuf, x, W1_rel, b1_rel, W1_root, h1);

    // ---- layer 2 ----
    gather64_v2<<<(N_NODES * 64 + 255) / 256, 256, 0, stream>>>(h1, adj, end_, deg, aggbuf);
    transform2_pool_reg<<<T_WAVES / 4, 256, 0, stream>>>(aggbuf, h1, W2_rel, b2_rel, W2_root, batch, sums);

    graph_counts<<<1, 256, 0, stream>>>(batch, counts);
    finalize<<<(N_GRAPHS * 64 + 255) / 256, 256, 0, stream>>>(sums, counts, out);
}

// Round 10
// 374.862 us; speedup vs baseline: 6.6723x; 1.0265x over previous
//
#include <hip/hip_runtime.h>

#define N_NODES 100000
#define N_EDGES 1600000
#define N_GRAPHS 256
#define F_IN 32
#define F_HID 64
#define F_OUT 64

#define T_WAVES 8192
#define NODES_PER_WAVE ((N_NODES + T_WAVES - 1) / T_WAVES)   // 13
#define NXCD 8
#define DPX ((N_NODES + NXCD - 1) / NXCD)    // 12500 dst nodes per XCD partition

// ---------------- CSR build ----------------
// XCD-partitioned histogram: all atomics on deg[d] for a given d come from one
// XCD-group of blocks -> deg lines stay in ONE per-XCD L2 (no cross-XCD ping-pong).
__global__ __launch_bounds__(256) void histogram_xcd(const int* __restrict__ dst,
                                                     int* __restrict__ deg) {
    int xcd = blockIdx.x & (NXCD - 1);
    int sub = blockIdx.x >> 3;
    int nsub = gridDim.x >> 3;
    int d_lo = xcd * DPX;
    int d_hi = min(d_lo + DPX, N_NODES);
    for (int e = sub * blockDim.x + threadIdx.x; e < N_EDGES; e += nsub * blockDim.x) {
        int d = __builtin_nontemporal_load(dst + e);
        if (d >= d_lo && d < d_hi) atomicAdd(&deg[d], 1);
    }
}

__global__ void scan1(const int* __restrict__ deg, int* __restrict__ end_, int* __restrict__ partials) {
    __shared__ int s[256];
    int tid = threadIdx.x;
    int i = blockIdx.x * 256 + tid;
    int v = (i < N_NODES) ? deg[i] : 0;
    s[tid] = v;
    __syncthreads();
#pragma unroll
    for (int off = 1; off < 256; off <<= 1) {
        int t = 0;
        if (tid >= off) t = s[tid - off];
        __syncthreads();
        if (tid >= off) s[tid] += t;
        __syncthreads();
    }
    if (i < N_NODES) end_[i] = s[tid];
    if (tid == 255) partials[blockIdx.x] = s[255];
}

__global__ void scan2(int* __restrict__ partials, int nb) {
    __shared__ int s[512];
    int tid = threadIdx.x;
    int v = (tid < nb) ? partials[tid] : 0;
    s[tid] = v;
    __syncthreads();
#pragma unroll
    for (int off = 1; off < 512; off <<= 1) {
        int t = 0;
        if (tid >= off) t = s[tid - off];
        __syncthreads();
        if (tid >= off) s[tid] += t;
        __syncthreads();
    }
    int excl = (tid > 0) ? s[tid - 1] : 0;
    if (tid < nb) partials[tid] = excl;
}

__global__ void scan3(const int* __restrict__ deg, int* __restrict__ end_,
                      int* __restrict__ cursor, const int* __restrict__ partials) {
    int i = blockIdx.x * 256 + threadIdx.x;
    if (i < N_NODES) {
        int e = end_[i] + partials[blockIdx.x];
        end_[i] = e;
        cursor[i] = e - deg[i];
    }
}

// XCD-partitioned fill: each XCD-group handles dst in its 12.5k range, so the
// ~0.8 MB active adj window (and 50 KB cursor window) live in ONE per-XCD L2
// until lines are fully dirty -> dense writeback instead of 8x partial lines.
__global__ __launch_bounds__(256) void fill_adj_xcd(const int* __restrict__ src,
                                                    const int* __restrict__ dst,
                                                    int* __restrict__ cursor,
                                                    int* __restrict__ adj) {
    int xcd = blockIdx.x & (NXCD - 1);
    int sub = blockIdx.x >> 3;
    int nsub = gridDim.x >> 3;
    int d_lo = xcd * DPX;
    int d_hi = min(d_lo + DPX, N_NODES);
    for (int e = sub * blockDim.x + threadIdx.x; e < N_EDGES; e += nsub * blockDim.x) {
        int d = __builtin_nontemporal_load(dst + e);
        if (d >= d_lo && d < d_hi) {
            int pos = atomicAdd(&cursor[d], 1);
            adj[pos] = __builtin_nontemporal_load(src + e);
        }
    }
}

// ---------------- float4 gathers ----------------
__global__ __launch_bounds__(256) void gather64_v2(const float* __restrict__ h,
        const int* __restrict__ adj, const int* __restrict__ end_, const int* __restrict__ deg,
        float* __restrict__ agg) {
    int node = (blockIdx.x * blockDim.x + threadIdx.x) >> 6;
    int lane = threadIdx.x & 63;
    if (node >= N_NODES) return;
    int e = end_[node];
    int d = deg[node];
    int s = e - d;
    int q = lane & 15;
    int r = lane >> 4;
    const float4* h4 = (const float4*)h;

    float ax = 0.f, ay = 0.f, az = 0.f, aw = 0.f;
    for (int base = 0; base < d; base += 8) {
        int i0 = base + r;
        int i1 = base + 4 + r;
        if (i0 < d) {
            int s0 = adj[s + i0];
            float4 v = h4[(size_t)s0 * 16 + q];
            ax += v.x; ay += v.y; az += v.z; aw += v.w;
        }
        if (i1 < d) {
            int s1 = adj[s + i1];
            float4 v = h4[(size_t)s1 * 16 + q];
            ax += v.x; ay += v.y; az += v.z; aw += v.w;
        }
    }
#pragma unroll
    for (int off = 16; off < 64; off <<= 1) {
        ax += __shfl_xor(ax, off);
        ay += __shfl_xor(ay, off);
        az += __shfl_xor(az, off);
        aw += __shfl_xor(aw, off);
    }
    if (r == 0) {
        float4 o; o.x = ax; o.y = ay; o.z = az; o.w = aw;
        ((float4*)agg)[(size_t)node * 16 + q] = o;
    }
}

__global__ __launch_bounds__(256) void gather32_v2(const float* __restrict__ xin,
        const int* __restrict__ adj, const int* __restrict__ end_, const int* __restrict__ deg,
        float* __restrict__ agg) {
    int node = (blockIdx.x * blockDim.x + threadIdx.x) >> 6;
    int lane = threadIdx.x & 63;
    if (node >= N_NODES) return;
    int e = end_[node];
    int d = deg[node];
    int s = e - d;
    int q = lane & 7;
    int r = lane >> 3;
    const float4* x4 = (const float4*)xin;

    float ax = 0.f, ay = 0.f, az = 0.f, aw = 0.f;
    for (int base = 0; base < d; base += 16) {
        int i0 = base + r;
        int i1 = base + 8 + r;
        if (i0 < d) {
            int s0 = adj[s + i0];
            float4 v = x4[(size_t)s0 * 8 + q];
            ax += v.x; ay += v.y; az += v.z; aw += v.w;
        }
        if (i1 < d) {
            int s1 = adj[s + i1];
            float4 v = x4[(size_t)s1 * 8 + q];
            ax += v.x; ay += v.y; az += v.z; aw += v.w;
        }
    }
#pragma unroll
    for (int off = 8; off < 64; off <<= 1) {
        ax += __shfl_xor(ax, off);
        ay += __shfl_xor(ay, off);
        az += __shfl_xor(az, off);
        aw += __shfl_xor(aw, off);
    }
    if (r == 0) {
        float4 o; o.x = ax; o.y = ay; o.z = az; o.w = aw;
        ((float4*)agg)[(size_t)node * 8 + q] = o;
    }
}

// ---------------- register-resident transforms (no LDS) ----------------
__global__ __launch_bounds__(256) void transform1_reg(const float* __restrict__ agg,
        const float* __restrict__ xin,
        const float* __restrict__ Wrel, const float* __restrict__ brel,
        const float* __restrict__ Wroot,
        float* __restrict__ h1) {
    int lane = threadIdx.x & 63;
    int wgid = __builtin_amdgcn_readfirstlane(blockIdx.x * 4 + (threadIdx.x >> 6));
    int n0 = wgid * NODES_PER_WAVE;
    if (n0 >= N_NODES) return;
    int n1 = min(n0 + NODES_PER_WAVE, N_NODES);

    float wrel[32], wroot[32];
#pragma unroll
    for (int k = 0; k < 32; ++k) {
        wrel[k] = Wrel[k * 64 + lane];
        wroot[k] = Wroot[k * 64 + lane];
    }
    float b = brel[lane];

    for (int node = n0; node < n1; ++node) {
        const float4* ar = (const float4*)(agg + (size_t)node * 32);
        const float4* xr = (const float4*)(xin + (size_t)node * 32);
        float o = b;
#pragma unroll
        for (int kk = 0; kk < 8; ++kk) {
            float4 a4 = ar[kk];
            float4 x4 = xr[kk];
            o += a4.x * wrel[kk * 4 + 0] + a4.y * wrel[kk * 4 + 1]
               + a4.z * wrel[kk * 4 + 2] + a4.w * wrel[kk * 4 + 3];
            o += x4.x * wroot[kk * 4 + 0] + x4.y * wroot[kk * 4 + 1]
               + x4.z * wroot[kk * 4 + 2] + x4.w * wroot[kk * 4 + 3];
        }
        h1[(size_t)node * 64 + lane] = tanhf(o);
    }
}

__global__ __launch_bounds__(256) void transform2_pool_reg(const float* __restrict__ agg,
        const float* __restrict__ h1,
        const float* __restrict__ Wrel, const float* __restrict__ brel,
        const float* __restrict__ Wroot,
        const int* __restrict__ batch,
        float* __restrict__ sums) {
    int lane = threadIdx.x & 63;
    int wgid = __builtin_amdgcn_readfirstlane(blockIdx.x * 4 + (threadIdx.x >> 6));
    int n0 = wgid * NODES_PER_WAVE;
    if (n0 >= N_NODES) return;
    int n1 = min(n0 + NODES_PER_WAVE, N_NODES);

    float wrel[64], wroot[64];
#pragma unroll
    for (int k = 0; k < 64; ++k) {
        wrel[k] = Wrel[k * 64 + lane];
        wroot[k] = Wroot[k * 64 + lane];
    }
    float b = brel[lane];

    float psum = 0.0f;
    int curg = batch[n0];
    for (int node = n0; node < n1; ++node) {
        const float4* ar = (const float4*)(agg + (size_t)node * 64);
        const float4* xr = (const float4*)(h1 + (size_t)node * 64);
        float o = b;
#pragma unroll
        for (int kk = 0; kk < 16; ++kk) {
            float4 a4 = ar[kk];
            float4 x4 = xr[kk];
            o += a4.x * wrel[kk * 4 + 0] + a4.y * wrel[kk * 4 + 1]
               + a4.z * wrel[kk * 4 + 2] + a4.w * wrel[kk * 4 + 3];
            o += x4.x * wroot[kk * 4 + 0] + x4.y * wroot[kk * 4 + 1]
               + x4.z * wroot[kk * 4 + 2] + x4.w * wroot[kk * 4 + 3];
        }
        float h2 = tanhf(o);
        int g = batch[node];
        if (g != curg) {
            atomicAdd(&sums[(size_t)curg * 64 + lane], psum);
            psum = 0.0f;
            curg = g;
        }
        psum += h2;
    }
    atomicAdd(&sums[(size_t)curg * 64 + lane], psum);
}

__global__ void graph_counts(const int* __restrict__ batch, float* __restrict__ counts) {
    int g = threadIdx.x;
    if (g >= N_GRAPHS) return;
    int lo = 0, hi = N_NODES;
    while (lo < hi) { int mid = (lo + hi) >> 1; if (batch[mid] < g) lo = mid + 1; else hi = mid; }
    int start = lo;
    lo = 0; hi = N_NODES;
    while (lo < hi) { int mid = (lo + hi) >> 1; if (batch[mid] <= g) lo = mid + 1; else hi = mid; }
    counts[g] = (float)(lo - start);
}

__global__ void finalize(const float* __restrict__ sums,
                         const float* __restrict__ counts,
                         float* __restrict__ out) {
    int i = blockIdx.x * blockDim.x + threadIdx.x;
    if (i < N_GRAPHS * 64) {
        float c = counts[i >> 6];
        out[i] = sums[i] / fmaxf(c, 1.0f);
    }
}

extern "C" void kernel_launch(void* const* d_in, const int* in_sizes, int n_in,
                              void* d_out, int out_size, void* d_ws, size_t ws_size,
                              hipStream_t stream) {
    const float* x       = (const float*)d_in[0];
    const int*   ei      = (const int*)d_in[1];
    const int*   batch   = (const int*)d_in[2];
    const float* W1_rel  = (const float*)d_in[3];
    const float* b1_rel  = (const float*)d_in[4];
    const float* W1_root = (const float*)d_in[5];
    const float* W2_rel  = (const float*)d_in[6];
    const float* b2_rel  = (const float*)d_in[7];
    const float* W2_root = (const float*)d_in[8];
    float* out = (float*)d_out;

    const int* src = ei;
    const int* dst = ei + N_EDGES;

    // ---- workspace layout (bytes) ----
    char* ws = (char*)d_ws;
    int*   deg      = (int*)(ws + 0);                 // 400000
    float* sums     = (float*)(ws + 400000);          // 65536
    float* counts   = (float*)(ws + 465536);          // 1024
    // ---- zero boundary: 466560 ----
    int*   end_     = (int*)(ws + 466560);            // 400000
    int*   cursor   = (int*)(ws + 866560);            // 400000
    int*   partials = (int*)(ws + 1266560);           // 2048
    int*   adj      = (int*)(ws + 1268608);           // 6400000
    float* aggbuf   = (float*)(ws + 7668608);         // 25600000 (agg1/agg2 shared)
    float* h1       = (float*)(ws + 33268608);        // 25600000

    hipMemsetAsync(d_ws, 0, 466560, stream);

    // ---- CSR build ----
    const int NB_NODE = (N_NODES + 255) / 256;
    histogram_xcd<<<2048, 256, 0, stream>>>(dst, deg);
    scan1<<<NB_NODE, 256, 0, stream>>>(deg, end_, partials);
    scan2<<<1, 512, 0, stream>>>(partials, NB_NODE);
    scan3<<<NB_NODE, 256, 0, stream>>>(deg, end_, cursor, partials);
    fill_adj_xcd<<<2048, 256, 0, stream>>>(src, dst, cursor, adj);

    // ---- layer 1 ----
    gather32_v2<<<(N_NODES * 64 + 255) / 256, 256, 0, stream>>>(x, adj, end_, deg, aggbuf);
    transform1_reg<<<T_WAVES / 4, 256, 0, stream>>>(aggbuf, x, W1_rel, b1_rel, W1_root, h1);

    // ---- layer 2 ----
    gather64_v2<<<(N_NODES * 64 + 255) / 256, 256, 0, stream>>>(h1, adj, end_, deg, aggbuf);
    transform2_pool_reg<<<T_WAVES / 4, 256, 0, stream>>>(aggbuf, h1, W2_rel, b2_rel, W2_root, batch, sums);

    graph_counts<<<1, 256, 0, stream>>>(batch, counts);
    finalize<<<(N_GRAPHS * 64 + 255) / 256, 256, 0, stream>>>(sums, counts, out);
}

// Round 11
// 368.865 us; speedup vs baseline: 6.7808x; 1.0163x over previous
//
#include <hip/hip_runtime.h>

#define N_NODES 100000
#define N_EDGES 1600000
#define N_GRAPHS 256
#define F_IN 32
#define F_HID 64
#define F_OUT 64

#define T_WAVES 8192
#define NODES_PER_WAVE ((N_NODES + T_WAVES - 1) / T_WAVES)   // 13
#define T2_BLOCKS 768           // 3 blocks/CU at ~170 VGPR (2-3 waves/SIMD)
#define T2_WAVES (T2_BLOCKS * 4)
#define NODES_PER_WAVE2 ((N_NODES + T2_WAVES - 1) / T2_WAVES)  // 33
#define NXCD 8
#define DPX ((N_NODES + NXCD - 1) / NXCD)

// ---------------- CSR build ----------------
__global__ __launch_bounds__(256) void histogram_xcd(const int* __restrict__ dst,
                                                     int* __restrict__ deg) {
    int xcd = blockIdx.x & (NXCD - 1);
    int sub = blockIdx.x >> 3;
    int nsub = gridDim.x >> 3;
    int d_lo = xcd * DPX;
    int d_hi = min(d_lo + DPX, N_NODES);
    for (int e = sub * blockDim.x + threadIdx.x; e < N_EDGES; e += nsub * blockDim.x) {
        int d = __builtin_nontemporal_load(dst + e);
        if (d >= d_lo && d < d_hi) atomicAdd(&deg[d], 1);
    }
}

__global__ void scan1(const int* __restrict__ deg, int* __restrict__ end_, int* __restrict__ partials) {
    __shared__ int s[256];
    int tid = threadIdx.x;
    int i = blockIdx.x * 256 + tid;
    int v = (i < N_NODES) ? deg[i] : 0;
    s[tid] = v;
    __syncthreads();
#pragma unroll
    for (int off = 1; off < 256; off <<= 1) {
        int t = 0;
        if (tid >= off) t = s[tid - off];
        __syncthreads();
        if (tid >= off) s[tid] += t;
        __syncthreads();
    }
    if (i < N_NODES) end_[i] = s[tid];
    if (tid == 255) partials[blockIdx.x] = s[255];
}

__global__ void scan2(int* __restrict__ partials, int nb) {
    __shared__ int s[512];
    int tid = threadIdx.x;
    int v = (tid < nb) ? partials[tid] : 0;
    s[tid] = v;
    __syncthreads();
#pragma unroll
    for (int off = 1; off < 512; off <<= 1) {
        int t = 0;
        if (tid >= off) t = s[tid - off];
        __syncthreads();
        if (tid >= off) s[tid] += t;
        __syncthreads();
    }
    int excl = (tid > 0) ? s[tid - 1] : 0;
    if (tid < nb) partials[tid] = excl;
}

__global__ void scan3(const int* __restrict__ deg, int* __restrict__ end_,
                      int* __restrict__ cursor, const int* __restrict__ partials) {
    int i = blockIdx.x * 256 + threadIdx.x;
    if (i < N_NODES) {
        int e = end_[i] + partials[blockIdx.x];
        end_[i] = e;
        cursor[i] = e - deg[i];
    }
}

__global__ __launch_bounds__(256) void fill_adj_xcd(const int* __restrict__ src,
                                                    const int* __restrict__ dst,
                                                    int* __restrict__ cursor,
                                                    int* __restrict__ adj) {
    int xcd = blockIdx.x & (NXCD - 1);
    int sub = blockIdx.x >> 3;
    int nsub = gridDim.x >> 3;
    int d_lo = xcd * DPX;
    int d_hi = min(d_lo + DPX, N_NODES);
    for (int e = sub * blockDim.x + threadIdx.x; e < N_EDGES; e += nsub * blockDim.x) {
        int d = __builtin_nontemporal_load(dst + e);
        if (d >= d_lo && d < d_hi) {
            int pos = atomicAdd(&cursor[d], 1);
            adj[pos] = __builtin_nontemporal_load(src + e);
        }
    }
}

// ---------------- float4 gathers ----------------
__global__ __launch_bounds__(256) void gather64_v2(const float* __restrict__ h,
        const int* __restrict__ adj, const int* __restrict__ end_, const int* __restrict__ deg,
        float* __restrict__ agg) {
    int node = (blockIdx.x * blockDim.x + threadIdx.x) >> 6;
    int lane = threadIdx.x & 63;
    if (node >= N_NODES) return;
    int e = end_[node];
    int d = deg[node];
    int s = e - d;
    int q = lane & 15;
    int r = lane >> 4;
    const float4* h4 = (const float4*)h;

    float ax = 0.f, ay = 0.f, az = 0.f, aw = 0.f;
    for (int base = 0; base < d; base += 8) {
        int i0 = base + r;
        int i1 = base + 4 + r;
        if (i0 < d) {
            int s0 = adj[s + i0];
            float4 v = h4[(size_t)s0 * 16 + q];
            ax += v.x; ay += v.y; az += v.z; aw += v.w;
        }
        if (i1 < d) {
            int s1 = adj[s + i1];
            float4 v = h4[(size_t)s1 * 16 + q];
            ax += v.x; ay += v.y; az += v.z; aw += v.w;
        }
    }
#pragma unroll
    for (int off = 16; off < 64; off <<= 1) {
        ax += __shfl_xor(ax, off);
        ay += __shfl_xor(ay, off);
        az += __shfl_xor(az, off);
        aw += __shfl_xor(aw, off);
    }
    if (r == 0) {
        float4 o; o.x = ax; o.y = ay; o.z = az; o.w = aw;
        ((float4*)agg)[(size_t)node * 16 + q] = o;
    }
}

__global__ __launch_bounds__(256) void gather32_v2(const float* __restrict__ xin,
        const int* __restrict__ adj, const int* __restrict__ end_, const int* __restrict__ deg,
        float* __restrict__ agg) {
    int node = (blockIdx.x * blockDim.x + threadIdx.x) >> 6;
    int lane = threadIdx.x & 63;
    if (node >= N_NODES) return;
    int e = end_[node];
    int d = deg[node];
    int s = e - d;
    int q = lane & 7;
    int r = lane >> 3;
    const float4* x4 = (const float4*)xin;

    float ax = 0.f, ay = 0.f, az = 0.f, aw = 0.f;
    for (int base = 0; base < d; base += 16) {
        int i0 = base + r;
        int i1 = base + 8 + r;
        if (i0 < d) {
            int s0 = adj[s + i0];
            float4 v = x4[(size_t)s0 * 8 + q];
            ax += v.x; ay += v.y; az += v.z; aw += v.w;
        }
        if (i1 < d) {
            int s1 = adj[s + i1];
            float4 v = x4[(size_t)s1 * 8 + q];
            ax += v.x; ay += v.y; az += v.z; aw += v.w;
        }
    }
#pragma unroll
    for (int off = 8; off < 64; off <<= 1) {
        ax += __shfl_xor(ax, off);
        ay += __shfl_xor(ay, off);
        az += __shfl_xor(az, off);
        aw += __shfl_xor(aw, off);
    }
    if (r == 0) {
        float4 o; o.x = ax; o.y = ay; o.z = az; o.w = aw;
        ((float4*)agg)[(size_t)node * 8 + q] = o;
    }
}

// ---------------- register-resident transforms ----------------
__global__ __launch_bounds__(256) void transform1_reg(const float* __restrict__ agg,
        const float* __restrict__ xin,
        const float* __restrict__ Wrel, const float* __restrict__ brel,
        const float* __restrict__ Wroot,
        float* __restrict__ h1) {
    int lane = threadIdx.x & 63;
    int wgid = __builtin_amdgcn_readfirstlane(blockIdx.x * 4 + (threadIdx.x >> 6));
    int n0 = wgid * NODES_PER_WAVE;
    if (n0 >= N_NODES) return;
    int n1 = min(n0 + NODES_PER_WAVE, N_NODES);

    float wrel[32], wroot[32];
#pragma unroll
    for (int k = 0; k < 32; ++k) {
        wrel[k] = Wrel[k * 64 + lane];
        wroot[k] = Wroot[k * 64 + lane];
    }
    float b = brel[lane];

    for (int node = n0; node < n1; ++node) {
        const float4* ar = (const float4*)(agg + (size_t)node * 32);
        const float4* xr = (const float4*)(xin + (size_t)node * 32);
        float o = b;
#pragma unroll
        for (int kk = 0; kk < 8; ++kk) {
            float4 a4 = ar[kk];
            float4 x4 = xr[kk];
            o += a4.x * wrel[kk * 4 + 0] + a4.y * wrel[kk * 4 + 1]
               + a4.z * wrel[kk * 4 + 2] + a4.w * wrel[kk * 4 + 3];
            o += x4.x * wroot[kk * 4 + 0] + x4.y * wroot[kk * 4 + 1]
               + x4.z * wroot[kk * 4 + 2] + x4.w * wroot[kk * 4 + 3];
        }
        h1[(size_t)node * 64 + lane] = tanhf(o);
    }
}

// Layer-2 transform + pool. __launch_bounds__(256,2) allows up to 256 VGPRs so
// the 128 weight values stay register-resident (R10: default cap forced
// re-loads every node, VGPR_Count=72). 2-node ILP hides FMA-chain + load latency.
__global__ __launch_bounds__(256, 2) void transform2_pool_reg(const float* __restrict__ agg,
        const float* __restrict__ h1,
        const float* __restrict__ Wrel, const float* __restrict__ brel,
        const float* __restrict__ Wroot,
        const int* __restrict__ batch,
        float* __restrict__ sums) {
    int lane = threadIdx.x & 63;
    int wgid = __builtin_amdgcn_readfirstlane(blockIdx.x * 4 + (threadIdx.x >> 6));
    int n0 = wgid * NODES_PER_WAVE2;
    if (n0 >= N_NODES) return;
    int n1 = min(n0 + NODES_PER_WAVE2, N_NODES);

    float wrel[64], wroot[64];
#pragma unroll
    for (int k = 0; k < 64; ++k) {
        wrel[k] = Wrel[k * 64 + lane];
        wroot[k] = Wroot[k * 64 + lane];
    }
    float b = brel[lane];

    float psum = 0.0f;
    int curg = batch[n0];
    int node = n0;
    for (; node + 1 < n1; node += 2) {
        const float4* ar0 = (const float4*)(agg + (size_t)node * 64);
        const float4* xr0 = (const float4*)(h1 + (size_t)node * 64);
        const float4* ar1 = (const float4*)(agg + (size_t)(node + 1) * 64);
        const float4* xr1 = (const float4*)(h1 + (size_t)(node + 1) * 64);
        float o0 = b, o1 = b;
#pragma unroll
        for (int kk = 0; kk < 16; ++kk) {
            float4 a0 = ar0[kk];
            float4 x0 = xr0[kk];
            float4 a1 = ar1[kk];
            float4 x1 = xr1[kk];
            o0 += a0.x * wrel[kk * 4 + 0] + a0.y * wrel[kk * 4 + 1]
                + a0.z * wrel[kk * 4 + 2] + a0.w * wrel[kk * 4 + 3];
            o1 += a1.x * wrel[kk * 4 + 0] + a1.y * wrel[kk * 4 + 1]
                + a1.z * wrel[kk * 4 + 2] + a1.w * wrel[kk * 4 + 3];
            o0 += x0.x * wroot[kk * 4 + 0] + x0.y * wroot[kk * 4 + 1]
                + x0.z * wroot[kk * 4 + 2] + x0.w * wroot[kk * 4 + 3];
            o1 += x1.x * wroot[kk * 4 + 0] + x1.y * wroot[kk * 4 + 1]
                + x1.z * wroot[kk * 4 + 2] + x1.w * wroot[kk * 4 + 3];
        }
        float h20 = tanhf(o0);
        float h21 = tanhf(o1);
        int g0 = batch[node];
        int g1 = batch[node + 1];
        if (g0 != curg) {
            atomicAdd(&sums[(size_t)curg * 64 + lane], psum);
            psum = 0.0f;
            curg = g0;
        }
        psum += h20;
        if (g1 != curg) {
            atomicAdd(&sums[(size_t)curg * 64 + lane], psum);
            psum = 0.0f;
            curg = g1;
        }
        psum += h21;
    }
    if (node < n1) {
        const float4* ar = (const float4*)(agg + (size_t)node * 64);
        const float4* xr = (const float4*)(h1 + (size_t)node * 64);
        float o = b;
#pragma unroll
        for (int kk = 0; kk < 16; ++kk) {
            float4 a4 = ar[kk];
            float4 x4 = xr[kk];
            o += a4.x * wrel[kk * 4 + 0] + a4.y * wrel[kk * 4 + 1]
               + a4.z * wrel[kk * 4 + 2] + a4.w * wrel[kk * 4 + 3];
            o += x4.x * wroot[kk * 4 + 0] + x4.y * wroot[kk * 4 + 1]
               + x4.z * wroot[kk * 4 + 2] + x4.w * wroot[kk * 4 + 3];
        }
        float h2 = tanhf(o);
        int g = batch[node];
        if (g != curg) {
            atomicAdd(&sums[(size_t)curg * 64 + lane], psum);
            psum = 0.0f;
            curg = g;
        }
        psum += h2;
    }
    atomicAdd(&sums[(size_t)curg * 64 + lane], psum);
}

__global__ void graph_counts(const int* __restrict__ batch, float* __restrict__ counts) {
    int g = threadIdx.x;
    if (g >= N_GRAPHS) return;
    int lo = 0, hi = N_NODES;
    while (lo < hi) { int mid = (lo + hi) >> 1; if (batch[mid] < g) lo = mid + 1; else hi = mid; }
    int start = lo;
    lo = 0; hi = N_NODES;
    while (lo < hi) { int mid = (lo + hi) >> 1; if (batch[mid] <= g) lo = mid + 1; else hi = mid; }
    counts[g] = (float)(lo - start);
}

__global__ void finalize(const float* __restrict__ sums,
                         const float* __restrict__ counts,
                         float* __restrict__ out) {
    int i = blockIdx.x * blockDim.x + threadIdx.x;
    if (i < N_GRAPHS * 64) {
        float c = counts[i >> 6];
        out[i] = sums[i] / fmaxf(c, 1.0f);
    }
}

extern "C" void kernel_launch(void* const* d_in, const int* in_sizes, int n_in,
                              void* d_out, int out_size, void* d_ws, size_t ws_size,
                              hipStream_t stream) {
    const float* x       = (const float*)d_in[0];
    const int*   ei      = (const int*)d_in[1];
    const int*   batch   = (const int*)d_in[2];
    const float* W1_rel  = (const float*)d_in[3];
    const float* b1_rel  = (const float*)d_in[4];
    const float* W1_root = (const float*)d_in[5];
    const float* W2_rel  = (const float*)d_in[6];
    const float* b2_rel  = (const float*)d_in[7];
    const float* W2_root = (const float*)d_in[8];
    float* out = (float*)d_out;

    const int* src = ei;
    const int* dst = ei + N_EDGES;

    // ---- workspace layout (bytes) ----
    char* ws = (char*)d_ws;
    int*   deg      = (int*)(ws + 0);                 // 400000
    float* sums     = (float*)(ws + 400000);          // 65536
    float* counts   = (float*)(ws + 465536);          // 1024
    // ---- zero boundary: 466560 ----
    int*   end_     = (int*)(ws + 466560);            // 400000
    int*   cursor   = (int*)(ws + 866560);            // 400000
    int*   partials = (int*)(ws + 1266560);           // 2048
    int*   adj      = (int*)(ws + 1268608);           // 6400000
    float* aggbuf   = (float*)(ws + 7668608);         // 25600000 (agg1/agg2 shared)
    float* h1       = (float*)(ws + 33268608);        // 25600000

    hipMemsetAsync(d_ws, 0, 466560, stream);

    // ---- CSR build ----
    const int NB_NODE = (N_NODES + 255) / 256;
    histogram_xcd<<<2048, 256, 0, stream>>>(dst, deg);
    scan1<<<NB_NODE, 256, 0, stream>>>(deg, end_, partials);
    scan2<<<1, 512, 0, stream>>>(partials, NB_NODE);
    scan3<<<NB_NODE, 256, 0, stream>>>(deg, end_, cursor, partials);
    fill_adj_xcd<<<2048, 256, 0, stream>>>(src, dst, cursor, adj);

    // ---- layer 1 ----
    gather32_v2<<<(N_NODES * 64 + 255) / 256, 256, 0, stream>>>(x, adj, end_, deg, aggbuf);
    transform1_reg<<<T_WAVES / 4, 256, 0, stream>>>(aggbuf, x, W1_rel, b1_rel, W1_root, h1);

    // ---- layer 2 ----
    gather64_v2<<<(N_NODES * 64 + 255) / 256, 256, 0, stream>>>(h1, adj, end_, deg, aggbuf);
    transform2_pool_reg<<<T2_BLOCKS, 256, 0, stream>>>(aggbuf, h1, W2_rel, b2_rel, W2_root, batch, sums);

    graph_counts<<<1, 256, 0, stream>>>(batch, counts);
    finalize<<<(N_GRAPHS * 64 + 255) / 256, 256, 0, stream>>>(sums, counts, out);
}